// Round 2
// baseline (13918.118 us; speedup 1.0000x reference)
//
#include <hip/hip_runtime.h>
#include <hip/hip_bf16.h>

#define B_ 2
#define T_ 512
#define D_ 512
#define H_ 8
#define L_ 6
#define F_ 2048
#define V_ 32000
#define BT_ (B_ * T_)
#define HD_ (H_ * D_)
#define BH_ (B_ * H_)

// ---------------- embedding * sqrt(D) + sinusoidal PE ----------------
__global__ __launch_bounds__(256) void embed_kernel(
    const int* __restrict__ tok, const float* __restrict__ emb, float* __restrict__ out)
{
  const int row = blockIdx.x;            // b*T + t
  const int t = row & (T_ - 1);
  const int token = tok[row];
  const float* e = emb + (size_t)token * D_;
  float* o = out + (size_t)row * D_;
  const float scale = sqrtf((float)D_);
  const float nl = -logf(10000.0f);
  for (int d = threadIdx.x; d < D_; d += 256) {
    int i = d >> 1;
    float wl = expf(nl * (2.0f * (float)i) / (float)D_);
    float ang = (float)t * wl;
    float pe = (d & 1) ? cosf(ang) : sinf(ang);
    o[d] = e[d] * scale + pe;
  }
}

// ---------------- C[M,N] = A[M,K](f32) @ W[K,N](f32) + bias, opt relu ----------------
// 64x64 tile, BK=16, 256 threads, 4x4 per-thread microtile.
template<bool RELU>
__global__ __launch_bounds__(256) void gemm_bias_kernel(
    const float* __restrict__ A, const float* __restrict__ W,
    const float* __restrict__ bias, float* __restrict__ C,
    int M, int N, int K)
{
  __shared__ float As[16][68];
  __shared__ float Bs[16][68];
  const int bm = blockIdx.y * 64, bn = blockIdx.x * 64;
  const int tid = threadIdx.x;
  const int tr = (tid >> 4) << 2, tc = (tid & 15) << 2;
  const int lr = tid >> 2, lk = (tid & 3) << 2;   // A-tile: row lr (0..63), k off lk
  const int wr = tid >> 4, wc = (tid & 15) << 2;  // W-tile: row wr (0..15), col wc
  float acc[4][4] = {};
  for (int k0 = 0; k0 < K; k0 += 16) {
    float4 av = *(const float4*)(A + (size_t)(bm + lr) * K + (k0 + lk));
    As[lk + 0][lr] = av.x; As[lk + 1][lr] = av.y;
    As[lk + 2][lr] = av.z; As[lk + 3][lr] = av.w;
    float4 wv = *(const float4*)(W + (size_t)(k0 + wr) * N + (bn + wc));
    Bs[wr][wc + 0] = wv.x; Bs[wr][wc + 1] = wv.y;
    Bs[wr][wc + 2] = wv.z; Bs[wr][wc + 3] = wv.w;
    __syncthreads();
#pragma unroll
    for (int kk = 0; kk < 16; ++kk) {
      float4 a4 = *(const float4*)&As[kk][tr];
      float4 b4 = *(const float4*)&Bs[kk][tc];
      float a[4] = {a4.x, a4.y, a4.z, a4.w};
      float b[4] = {b4.x, b4.y, b4.z, b4.w};
#pragma unroll
      for (int i = 0; i < 4; ++i)
#pragma unroll
        for (int j = 0; j < 4; ++j)
          acc[i][j] += a[i] * b[j];
    }
    __syncthreads();
  }
#pragma unroll
  for (int i = 0; i < 4; ++i) {
    const size_t rowo = (size_t)(bm + tr + i) * N;
#pragma unroll
    for (int j = 0; j < 4; ++j) {
      const int col = bn + tc + j;
      float v = acc[i][j] + bias[col];
      if (RELU) v = fmaxf(v, 0.0f);
      C[rowo + col] = v;
    }
  }
}

// ---------------- S[bh][q][k] = (Q[b,q,h,:] . K[b,k,h,:]) / sqrt(D) ----------------
__global__ __launch_bounds__(256) void qk_kernel(
    const float* __restrict__ Q, const float* __restrict__ Kt, float* __restrict__ S)
{
  const int bh = blockIdx.z;
  const int b = bh >> 3, h = bh & (H_ - 1);
  const float* Ab = Q  + (size_t)b * T_ * HD_ + (size_t)h * D_;  // lda = HD_
  const float* Bb = Kt + (size_t)b * T_ * HD_ + (size_t)h * D_;  // ldb = HD_
  float* Cb = S + (size_t)bh * T_ * T_;
  const int bm = blockIdx.y * 64, bn = blockIdx.x * 64;
  const int tid = threadIdx.x;
  const int tr = (tid >> 4) << 2, tc = (tid & 15) << 2;
  const int lr = tid >> 2, lk = (tid & 3) << 2;
  __shared__ float As[16][68];
  __shared__ float Bs[16][68];
  float acc[4][4] = {};
  for (int k0 = 0; k0 < D_; k0 += 16) {
    float4 av = *(const float4*)(Ab + (size_t)(bm + lr) * HD_ + (k0 + lk));
    As[lk + 0][lr] = av.x; As[lk + 1][lr] = av.y;
    As[lk + 2][lr] = av.z; As[lk + 3][lr] = av.w;
    float4 bv = *(const float4*)(Bb + (size_t)(bn + lr) * HD_ + (k0 + lk));
    Bs[lk + 0][lr] = bv.x; Bs[lk + 1][lr] = bv.y;
    Bs[lk + 2][lr] = bv.z; Bs[lk + 3][lr] = bv.w;
    __syncthreads();
#pragma unroll
    for (int kk = 0; kk < 16; ++kk) {
      float4 a4 = *(const float4*)&As[kk][tr];
      float4 b4 = *(const float4*)&Bs[kk][tc];
      float a[4] = {a4.x, a4.y, a4.z, a4.w};
      float b[4] = {b4.x, b4.y, b4.z, b4.w};
#pragma unroll
      for (int i = 0; i < 4; ++i)
#pragma unroll
        for (int j = 0; j < 4; ++j)
          acc[i][j] += a[i] * b[j];
    }
    __syncthreads();
  }
  const float scale = 0.044194173824159216f;  // 1/sqrt(512)
#pragma unroll
  for (int i = 0; i < 4; ++i)
#pragma unroll
    for (int j = 0; j < 4; ++j)
      Cb[(size_t)(bm + tr + i) * T_ + (bn + tc + j)] = acc[i][j] * scale;
}

// ---------------- row softmax over k; causal limits k<=q; masked tail -> 0 ----------------
__global__ __launch_bounds__(256) void softmax_kernel(float* __restrict__ S, int causal)
{
  __shared__ float red[256];
  const int q = blockIdx.x, bh = blockIdx.y, tid = threadIdx.x;
  float* row = S + ((size_t)bh * T_ + q) * T_;
  const int n = causal ? (q + 1) : T_;
  float mx = -3.0e38f;
  for (int k = tid; k < n; k += 256) mx = fmaxf(mx, row[k]);
  red[tid] = mx; __syncthreads();
  for (int o = 128; o > 0; o >>= 1) { if (tid < o) red[tid] = fmaxf(red[tid], red[tid + o]); __syncthreads(); }
  const float m = red[0]; __syncthreads();
  float s = 0.0f;
  for (int k = tid; k < n; k += 256) { float e = expf(row[k] - m); row[k] = e; s += e; }
  red[tid] = s; __syncthreads();
  for (int o = 128; o > 0; o >>= 1) { if (tid < o) red[tid] += red[tid + o]; __syncthreads(); }
  const float inv = 1.0f / red[0];
  __syncthreads();
  for (int k = tid; k < n; k += 256) row[k] *= inv;
  for (int k = n + tid; k < T_; k += 256) row[k] = 0.0f;
}

// ---------------- O[b,q,h,:] = sum_k P[bh][q][k] * V[b,k,h,:] ----------------
__global__ __launch_bounds__(256) void pv_kernel(
    const float* __restrict__ P, const float* __restrict__ V, float* __restrict__ O)
{
  const int bh = blockIdx.z;
  const int b = bh >> 3, h = bh & (H_ - 1);
  const float* Ab = P + (size_t)bh * T_ * T_;                    // lda = T_
  const float* Bb = V + (size_t)b * T_ * HD_ + (size_t)h * D_;   // ldb = HD_
  float* Cb = O + (size_t)b * T_ * HD_ + (size_t)h * D_;         // ldc = HD_
  const int bm = blockIdx.y * 64, bn = blockIdx.x * 64;
  const int tid = threadIdx.x;
  const int tr = (tid >> 4) << 2, tc = (tid & 15) << 2;
  const int lr = tid >> 2, lk = (tid & 3) << 2;
  const int wr = tid >> 4, wc = (tid & 15) << 2;
  __shared__ float As[16][68];
  __shared__ float Bs[16][68];
  float acc[4][4] = {};
  for (int k0 = 0; k0 < T_; k0 += 16) {
    float4 av = *(const float4*)(Ab + (size_t)(bm + lr) * T_ + (k0 + lk));
    As[lk + 0][lr] = av.x; As[lk + 1][lr] = av.y;
    As[lk + 2][lr] = av.z; As[lk + 3][lr] = av.w;
    float4 bv = *(const float4*)(Bb + (size_t)(k0 + wr) * HD_ + (bn + wc));
    Bs[wr][wc + 0] = bv.x; Bs[wr][wc + 1] = bv.y;
    Bs[wr][wc + 2] = bv.z; Bs[wr][wc + 3] = bv.w;
    __syncthreads();
#pragma unroll
    for (int kk = 0; kk < 16; ++kk) {
      float4 a4 = *(const float4*)&As[kk][tr];
      float4 b4 = *(const float4*)&Bs[kk][tc];
      float a[4] = {a4.x, a4.y, a4.z, a4.w};
      float b[4] = {b4.x, b4.y, b4.z, b4.w};
#pragma unroll
      for (int i = 0; i < 4; ++i)
#pragma unroll
        for (int j = 0; j < 4; ++j)
          acc[i][j] += a[i] * b[j];
    }
    __syncthreads();
  }
#pragma unroll
  for (int i = 0; i < 4; ++i)
#pragma unroll
    for (int j = 0; j < 4; ++j)
      Cb[(size_t)(bm + tr + i) * HD_ + (bn + tc + j)] = acc[i][j];
}

// ---------------- h = LayerNorm(a + h) * g + b (in place on h) ----------------
__global__ __launch_bounds__(256) void add_ln_kernel(
    const float* __restrict__ a, float* __restrict__ h,
    const float* __restrict__ g, const float* __restrict__ b)
{
  __shared__ float red[256];
  const int row = blockIdx.x, tid = threadIdx.x;
  const float* ar = a + (size_t)row * D_;
  float* hr = h + (size_t)row * D_;
  float x0 = ar[tid] + hr[tid];
  float x1 = ar[tid + 256] + hr[tid + 256];
  red[tid] = x0 + x1;
  __syncthreads();
  for (int o = 128; o > 0; o >>= 1) { if (tid < o) red[tid] += red[tid + o]; __syncthreads(); }
  const float mean = red[0] * (1.0f / D_);
  __syncthreads();
  const float d0 = x0 - mean, d1 = x1 - mean;
  red[tid] = d0 * d0 + d1 * d1;
  __syncthreads();
  for (int o = 128; o > 0; o >>= 1) { if (tid < o) red[tid] += red[tid + o]; __syncthreads(); }
  const float inv = rsqrtf(red[0] * (1.0f / D_) + 1e-6f);
  hr[tid]       = d0 * inv * g[tid]       + b[tid];
  hr[tid + 256] = d1 * inv * g[tid + 256] + b[tid + 256];
}

extern "C" void kernel_launch(void* const* d_in, const int* in_sizes, int n_in,
                              void* d_out, int out_size, void* d_ws, size_t ws_size,
                              hipStream_t stream)
{
  const int*   x         = (const int*)d_in[0];
  const int*   y         = (const int*)d_in[1];
  const float* enc_emb   = (const float*)d_in[2];
  const float* dec_emb   = (const float*)d_in[3];
  const float* enc_qkv_w = (const float*)d_in[4];
  const float* enc_qkv_b = (const float*)d_in[5];
  const float* enc_out_w = (const float*)d_in[6];
  const float* enc_out_b = (const float*)d_in[7];
  const float* enc_ln1_g = (const float*)d_in[8];
  const float* enc_ln1_b = (const float*)d_in[9];
  const float* enc_ff_w1 = (const float*)d_in[10];
  const float* enc_ff_b1 = (const float*)d_in[11];
  const float* enc_ff_w2 = (const float*)d_in[12];
  const float* enc_ff_b2 = (const float*)d_in[13];
  const float* enc_ln2_g = (const float*)d_in[14];
  const float* enc_ln2_b = (const float*)d_in[15];
  const float* dec_sa_qkv_w = (const float*)d_in[16];
  const float* dec_sa_qkv_b = (const float*)d_in[17];
  const float* dec_sa_out_w = (const float*)d_in[18];
  const float* dec_sa_out_b = (const float*)d_in[19];
  const float* dec_ln1_g = (const float*)d_in[20];
  const float* dec_ln1_b = (const float*)d_in[21];
  const float* dec_ca_qkv_w = (const float*)d_in[22];
  const float* dec_ca_qkv_b = (const float*)d_in[23];
  const float* dec_ca_out_w = (const float*)d_in[24];
  const float* dec_ca_out_b = (const float*)d_in[25];
  const float* dec_ln2_g = (const float*)d_in[26];
  const float* dec_ln2_b = (const float*)d_in[27];
  const float* dec_ff_w1 = (const float*)d_in[28];
  const float* dec_ff_b1 = (const float*)d_in[29];
  const float* dec_ff_w2 = (const float*)d_in[30];
  const float* dec_ff_b2 = (const float*)d_in[31];
  const float* dec_ln3_g = (const float*)d_in[32];
  const float* dec_ln3_b = (const float*)d_in[33];
  const float* head_w    = (const float*)d_in[34];
  const float* head_b    = (const float*)d_in[35];
  float* out = (float*)d_out;

  // workspace carve-up (fp32). Total = 3*BT*D + 3*BT*HD + BH*T*T floats ~ 73.4 MB.
  float* ws = (float*)d_ws;
  size_t off = 0;
  float* h  = ws + off; off += (size_t)BT_ * D_;
  float* dd = ws + off; off += (size_t)BT_ * D_;
  float* aa = ws + off; off += (size_t)BT_ * D_;
  float* Qb = ws + off; off += (size_t)BT_ * HD_;
  float* Kb = ws + off; off += (size_t)BT_ * HD_;
  float* Vb = ws + off; off += (size_t)BT_ * HD_;
  float* Sb = ws + off; off += (size_t)BH_ * T_ * T_;
  float* Ob  = Qb;   // Q dead after qk_kernel
  float* mid = Qb;   // attn buffers dead during FFN

  dim3 blk(256);

  auto gemm_f = [&](const float* A, const float* W, const float* bias, float* C,
                    int M, int N, int K, bool relu) {
    dim3 g(N / 64, M / 64);
    if (relu) gemm_bias_kernel<true ><<<g, blk, 0, stream>>>(A, W, bias, C, M, N, K);
    else      gemm_bias_kernel<false><<<g, blk, 0, stream>>>(A, W, bias, C, M, N, K);
  };

  auto attention = [&](const float* qsrc, const float* kvsrc,
                       const float* qkvw, const float* qkvb,
                       const float* ow, const float* ob, int causal) {
    gemm_f(qsrc,  qkvw + 0 * (size_t)D_ * HD_, qkvb + 0 * HD_, Qb, BT_, HD_, D_, false);
    gemm_f(kvsrc, qkvw + 1 * (size_t)D_ * HD_, qkvb + 1 * HD_, Kb, BT_, HD_, D_, false);
    gemm_f(kvsrc, qkvw + 2 * (size_t)D_ * HD_, qkvb + 2 * HD_, Vb, BT_, HD_, D_, false);
    qk_kernel<<<dim3(T_ / 64, T_ / 64, BH_), blk, 0, stream>>>(Qb, Kb, Sb);
    softmax_kernel<<<dim3(T_, BH_), blk, 0, stream>>>(Sb, causal);
    pv_kernel<<<dim3(D_ / 64, T_ / 64, BH_), blk, 0, stream>>>(Sb, Vb, Ob);
    gemm_f(Ob, ow, ob, aa, BT_, D_, HD_, false);
  };

  auto add_ln = [&](const float* a_, float* h_, const float* g_, const float* b_) {
    add_ln_kernel<<<dim3(BT_), blk, 0, stream>>>(a_, h_, g_, b_);
  };

  // ---------------- encoder ----------------
  embed_kernel<<<dim3(BT_), blk, 0, stream>>>(x, enc_emb, h);
  for (int i = 0; i < L_; ++i) {
    attention(h, h,
              enc_qkv_w + (size_t)i * 3 * D_ * HD_, enc_qkv_b + (size_t)i * 3 * HD_,
              enc_out_w + (size_t)i * HD_ * D_, enc_out_b + (size_t)i * D_, 0);
    add_ln(aa, h, enc_ln1_g + (size_t)i * D_, enc_ln1_b + (size_t)i * D_);
    gemm_f(h,   enc_ff_w1 + (size_t)i * D_ * F_, enc_ff_b1 + (size_t)i * F_, mid, BT_, F_, D_, true);
    gemm_f(mid, enc_ff_w2 + (size_t)i * F_ * D_, enc_ff_b2 + (size_t)i * D_, aa,  BT_, D_, F_, false);
    add_ln(aa, h, enc_ln2_g + (size_t)i * D_, enc_ln2_b + (size_t)i * D_);
  }

  // ---------------- decoder ----------------
  embed_kernel<<<dim3(BT_), blk, 0, stream>>>(y, dec_emb, dd);
  for (int i = 0; i < L_; ++i) {
    attention(dd, dd,
              dec_sa_qkv_w + (size_t)i * 3 * D_ * HD_, dec_sa_qkv_b + (size_t)i * 3 * HD_,
              dec_sa_out_w + (size_t)i * HD_ * D_, dec_sa_out_b + (size_t)i * D_, 1);
    add_ln(aa, dd, dec_ln1_g + (size_t)i * D_, dec_ln1_b + (size_t)i * D_);
    attention(dd, h,
              dec_ca_qkv_w + (size_t)i * 3 * D_ * HD_, dec_ca_qkv_b + (size_t)i * 3 * HD_,
              dec_ca_out_w + (size_t)i * HD_ * D_, dec_ca_out_b + (size_t)i * D_, 0);
    add_ln(aa, dd, dec_ln2_g + (size_t)i * D_, dec_ln2_b + (size_t)i * D_);
    gemm_f(dd,  dec_ff_w1 + (size_t)i * D_ * F_, dec_ff_b1 + (size_t)i * F_, mid, BT_, F_, D_, true);
    gemm_f(mid, dec_ff_w2 + (size_t)i * F_ * D_, dec_ff_b2 + (size_t)i * D_, aa,  BT_, D_, F_, false);
    add_ln(aa, dd, dec_ln3_g + (size_t)i * D_, dec_ln3_b + (size_t)i * D_);
  }

  // ---------------- LM head -> f32 logits ----------------
  gemm_bias_kernel<false><<<dim3(V_ / 64, BT_ / 64), blk, 0, stream>>>(
      dd, head_w, head_b, out, BT_, V_, D_);
}

// Round 3
// 3993.403 us; speedup vs baseline: 3.4853x; 3.4853x over previous
//
#include <hip/hip_runtime.h>
#include <hip/hip_bf16.h>

#define B_ 2
#define T_ 512
#define D_ 512
#define H_ 8
#define L_ 6
#define F_ 2048
#define V_ 32000
#define BT_ (B_ * T_)
#define HD_ (H_ * D_)
#define BH_ (B_ * H_)

typedef __attribute__((ext_vector_type(8))) short short8;
typedef __attribute__((ext_vector_type(4))) float f32x4;

__device__ __forceinline__ short f2b(float f) {
  __hip_bfloat16 h = __float2bfloat16(f);
  short u; __builtin_memcpy(&u, &h, 2); return u;
}

// ---------------- embedding * sqrt(D) + sinusoidal PE ----------------
__global__ __launch_bounds__(256) void embed_kernel(
    const int* __restrict__ tok, const float* __restrict__ emb, float* __restrict__ out)
{
  const int row = blockIdx.x;            // b*T + t
  const int t = row & (T_ - 1);
  const int token = tok[row];
  const float* e = emb + (size_t)token * D_;
  float* o = out + (size_t)row * D_;
  const float scale = sqrtf((float)D_);
  const float nl = -logf(10000.0f);
  for (int d = threadIdx.x; d < D_; d += 256) {
    int i = d >> 1;
    float wl = expf(nl * (2.0f * (float)i) / (float)D_);
    float ang = (float)t * wl;
    float pe = (d & 1) ? cosf(ang) : sinf(ang);
    o[d] = e[d] * scale + pe;
  }
}

// ---------------- generic bf16-MFMA GEMM ----------------
// C[M,N] (+bias)*scale = A[M,K](f32) @ B(f32); BT: B stored [N][K] (k-contig)
// else B stored [K][N]. 128x128 tile, BK=64, 4 waves. Batched via z (nh heads
// per batch for addressing) OR split-K via z (partials at kz*pstride).
// LDS layout chunk-major: Xs[chunk=k/8][128][8 bf16] -> all b128 ops conflict-free.
template<bool BT>
__global__ __launch_bounds__(256) void mfma_gemm(
    const float* __restrict__ A, long lda, long a_hi, long a_lo,
    const float* __restrict__ B, long ldb, long b_hi, long b_lo,
    float* __restrict__ C, long ldc, long c_hi, long c_lo, long pstride,
    int M, int N, int K, int nh, int ksplit, float scale,
    const float* __restrict__ bias)
{
  __shared__ short8 As8[8 * 128];
  __shared__ short8 Bs8[8 * 128];
  const int tid = threadIdx.x;
  const int bh = blockIdx.z / ksplit;
  const int kz = blockIdx.z % ksplit;
  const int bb = bh / nh, hh = bh % nh;
  const float* Ab = A + (long)bb * a_hi + (long)hh * a_lo;
  const float* Bb = B + (long)bb * b_hi + (long)hh * b_lo;
  float* Cb = C + (long)bb * c_hi + (long)hh * c_lo + (long)kz * pstride;
  const int bm = blockIdx.y * 128, bn = blockIdx.x * 128;
  const int klen = K / ksplit, kbase = kz * klen;
  const int lane = tid & 63, wid = tid >> 6;
  const int wr = wid >> 1, wc = wid & 1;
  const int g = lane >> 4, r16 = lane & 15;
  f32x4 acc[4][4] = {};

  for (int k0 = kbase; k0 < kbase + klen; k0 += 64) {
    // ---- stage A tile 128x64 ----
#pragma unroll
    for (int u = 0; u < 4; ++u) {
      int o = u * 256 + tid;          // 0..1023 octs
      int row = o >> 3, c = o & 7;
      const float* src = Ab + (long)(bm + row) * lda + (k0 + c * 8);
      float4 f0 = *(const float4*)(src);
      float4 f1 = *(const float4*)(src + 4);
      short8 v;
      v[0] = f2b(f0.x); v[1] = f2b(f0.y); v[2] = f2b(f0.z); v[3] = f2b(f0.w);
      v[4] = f2b(f1.x); v[5] = f2b(f1.y); v[6] = f2b(f1.z); v[7] = f2b(f1.w);
      As8[c * 128 + row] = v;
    }
    // ---- stage B tile 64x128 ----
    if (BT) {
#pragma unroll
      for (int u = 0; u < 4; ++u) {
        int o = u * 256 + tid;
        int col = o >> 3, c = o & 7;
        const float* src = Bb + (long)(bn + col) * ldb + (k0 + c * 8);
        float4 f0 = *(const float4*)(src);
        float4 f1 = *(const float4*)(src + 4);
        short8 v;
        v[0] = f2b(f0.x); v[1] = f2b(f0.y); v[2] = f2b(f0.z); v[3] = f2b(f0.w);
        v[4] = f2b(f1.x); v[5] = f2b(f1.y); v[6] = f2b(f1.z); v[7] = f2b(f1.w);
        Bs8[c * 128 + col] = v;
      }
    } else {
      const int col = tid & 127, sh = tid >> 7;
      const float* src = Bb + (long)(k0 + sh * 32) * ldb + (bn + col);
#pragma unroll
      for (int i = 0; i < 4; ++i) {
        short8 v;
#pragma unroll
        for (int j = 0; j < 8; ++j) v[j] = f2b(src[(long)(i * 8 + j) * ldb]);
        Bs8[(sh * 4 + i) * 128 + col] = v;
      }
    }
    __syncthreads();
    // ---- MFMA: 2 kb-halves x 4m x 4n ----
#pragma unroll
    for (int kb = 0; kb < 2; ++kb) {
      const int ch = (kb * 4 + g) * 128;
      short8 a0 = As8[ch + wr * 64 +  0 + r16];
      short8 a1 = As8[ch + wr * 64 + 16 + r16];
      short8 a2 = As8[ch + wr * 64 + 32 + r16];
      short8 a3 = As8[ch + wr * 64 + 48 + r16];
#pragma unroll
      for (int n = 0; n < 4; ++n) {
        short8 b = Bs8[ch + wc * 64 + n * 16 + r16];
        acc[0][n] = __builtin_amdgcn_mfma_f32_16x16x32_bf16(a0, b, acc[0][n], 0, 0, 0);
        acc[1][n] = __builtin_amdgcn_mfma_f32_16x16x32_bf16(a1, b, acc[1][n], 0, 0, 0);
        acc[2][n] = __builtin_amdgcn_mfma_f32_16x16x32_bf16(a2, b, acc[2][n], 0, 0, 0);
        acc[3][n] = __builtin_amdgcn_mfma_f32_16x16x32_bf16(a3, b, acc[3][n], 0, 0, 0);
      }
    }
    __syncthreads();
  }
  // ---- epilogue: col = lane&15, row = (lane>>4)*4 + reg ----
#pragma unroll
  for (int m = 0; m < 4; ++m) {
#pragma unroll
    for (int rr = 0; rr < 4; ++rr) {
      const int row = bm + wr * 64 + m * 16 + g * 4 + rr;
      float* crow = Cb + (long)row * ldc + bn + wc * 64 + r16;
#pragma unroll
      for (int n = 0; n < 4; ++n) {
        float v = acc[m][n][rr] * scale;
        if (bias) v += bias[bn + wc * 64 + n * 16 + r16];
        crow[n * 16] = v;
      }
    }
  }
}

// ---------------- split-K reduce: out = sum_z partial + bias (opt relu) ----------------
__global__ __launch_bounds__(256) void reduce_bias_kernel(
    const float* __restrict__ P, long pstride, int ks,
    const float* __restrict__ bias, int relu,
    float* __restrict__ out, long mn, int N)
{
  const long i = ((long)blockIdx.x * 256 + threadIdx.x) * 4;
  if (i >= mn) return;
  float4 s = *(const float4*)(P + i);
  for (int z = 1; z < ks; ++z) {
    float4 t = *(const float4*)(P + (long)z * pstride + i);
    s.x += t.x; s.y += t.y; s.z += t.z; s.w += t.w;
  }
  const int col = (int)(i % N);
  s.x += bias[col]; s.y += bias[col + 1]; s.z += bias[col + 2]; s.w += bias[col + 3];
  if (relu) {
    s.x = fmaxf(s.x, 0.f); s.y = fmaxf(s.y, 0.f);
    s.z = fmaxf(s.z, 0.f); s.w = fmaxf(s.w, 0.f);
  }
  *(float4*)(out + i) = s;
}

// ---------------- row softmax over k; causal limits k<=q; masked tail -> 0 ----------------
__global__ __launch_bounds__(256) void softmax_kernel(float* __restrict__ S, int causal)
{
  __shared__ float red[256];
  const int q = blockIdx.x, bh = blockIdx.y, tid = threadIdx.x;
  float* row = S + ((size_t)bh * T_ + q) * T_;
  const int n = causal ? (q + 1) : T_;
  float mx = -3.0e38f;
  for (int k = tid; k < n; k += 256) mx = fmaxf(mx, row[k]);
  red[tid] = mx; __syncthreads();
  for (int o = 128; o > 0; o >>= 1) { if (tid < o) red[tid] = fmaxf(red[tid], red[tid + o]); __syncthreads(); }
  const float m = red[0]; __syncthreads();
  float s = 0.0f;
  for (int k = tid; k < n; k += 256) { float e = expf(row[k] - m); row[k] = e; s += e; }
  red[tid] = s; __syncthreads();
  for (int o = 128; o > 0; o >>= 1) { if (tid < o) red[tid] += red[tid + o]; __syncthreads(); }
  const float inv = 1.0f / red[0];
  __syncthreads();
  for (int k = tid; k < n; k += 256) row[k] *= inv;
  for (int k = n + tid; k < T_; k += 256) row[k] = 0.0f;
}

// ---------------- h = LayerNorm(a + h) * g + b (in place on h) ----------------
__global__ __launch_bounds__(256) void add_ln_kernel(
    const float* __restrict__ a, float* __restrict__ h,
    const float* __restrict__ g, const float* __restrict__ b)
{
  __shared__ float red[256];
  const int row = blockIdx.x, tid = threadIdx.x;
  const float* ar = a + (size_t)row * D_;
  float* hr = h + (size_t)row * D_;
  float x0 = ar[tid] + hr[tid];
  float x1 = ar[tid + 256] + hr[tid + 256];
  red[tid] = x0 + x1;
  __syncthreads();
  for (int o = 128; o > 0; o >>= 1) { if (tid < o) red[tid] += red[tid + o]; __syncthreads(); }
  const float mean = red[0] * (1.0f / D_);
  __syncthreads();
  const float d0 = x0 - mean, d1 = x1 - mean;
  red[tid] = d0 * d0 + d1 * d1;
  __syncthreads();
  for (int o = 128; o > 0; o >>= 1) { if (tid < o) red[tid] += red[tid + o]; __syncthreads(); }
  const float inv = rsqrtf(red[0] * (1.0f / D_) + 1e-6f);
  hr[tid]       = d0 * inv * g[tid]       + b[tid];
  hr[tid + 256] = d1 * inv * g[tid + 256] + b[tid + 256];
}

extern "C" void kernel_launch(void* const* d_in, const int* in_sizes, int n_in,
                              void* d_out, int out_size, void* d_ws, size_t ws_size,
                              hipStream_t stream)
{
  const int*   x         = (const int*)d_in[0];
  const int*   y         = (const int*)d_in[1];
  const float* enc_emb   = (const float*)d_in[2];
  const float* dec_emb   = (const float*)d_in[3];
  const float* enc_qkv_w = (const float*)d_in[4];
  const float* enc_qkv_b = (const float*)d_in[5];
  const float* enc_out_w = (const float*)d_in[6];
  const float* enc_out_b = (const float*)d_in[7];
  const float* enc_ln1_g = (const float*)d_in[8];
  const float* enc_ln1_b = (const float*)d_in[9];
  const float* enc_ff_w1 = (const float*)d_in[10];
  const float* enc_ff_b1 = (const float*)d_in[11];
  const float* enc_ff_w2 = (const float*)d_in[12];
  const float* enc_ff_b2 = (const float*)d_in[13];
  const float* enc_ln2_g = (const float*)d_in[14];
  const float* enc_ln2_b = (const float*)d_in[15];
  const float* dec_sa_qkv_w = (const float*)d_in[16];
  const float* dec_sa_qkv_b = (const float*)d_in[17];
  const float* dec_sa_out_w = (const float*)d_in[18];
  const float* dec_sa_out_b = (const float*)d_in[19];
  const float* dec_ln1_g = (const float*)d_in[20];
  const float* dec_ln1_b = (const float*)d_in[21];
  const float* dec_ca_qkv_w = (const float*)d_in[22];
  const float* dec_ca_qkv_b = (const float*)d_in[23];
  const float* dec_ca_out_w = (const float*)d_in[24];
  const float* dec_ca_out_b = (const float*)d_in[25];
  const float* dec_ln2_g = (const float*)d_in[26];
  const float* dec_ln2_b = (const float*)d_in[27];
  const float* dec_ff_w1 = (const float*)d_in[28];
  const float* dec_ff_b1 = (const float*)d_in[29];
  const float* dec_ff_w2 = (const float*)d_in[30];
  const float* dec_ff_b2 = (const float*)d_in[31];
  const float* dec_ln3_g = (const float*)d_in[32];
  const float* dec_ln3_b = (const float*)d_in[33];
  const float* head_w    = (const float*)d_in[34];
  const float* head_b    = (const float*)d_in[35];
  float* out = (float*)d_out;

  // workspace carve-up (fp32). ~73.4 MB total; Sb doubles as split-K partial.
  float* ws = (float*)d_ws;
  size_t off = 0;
  float* h  = ws + off; off += (size_t)BT_ * D_;
  float* dd = ws + off; off += (size_t)BT_ * D_;
  float* aa = ws + off; off += (size_t)BT_ * D_;
  float* Qb = ws + off; off += (size_t)BT_ * HD_;
  float* Kb = ws + off; off += (size_t)BT_ * HD_;
  float* Vb = ws + off; off += (size_t)BT_ * HD_;
  float* Sb = ws + off; off += (size_t)BH_ * T_ * T_;   // 16.78 MB = split-K partial too
  float* Ob  = Qb;   // Q dead after qk
  float* mid = Qb;   // attn buffers dead during FFN

  dim3 blk(256);
  const long TT = (long)T_ * T_;
  const long THD = (long)T_ * HD_;

  auto gemm = [&](bool bt, const float* A, long lda, long a_hi, long a_lo,
                  const float* Bp, long ldb, long b_hi, long b_lo,
                  float* Cp, long ldc, long c_hi, long c_lo, long pstride,
                  int M, int N, int K, int batch, int nh, int ksplit,
                  float scale, const float* bias) {
    dim3 g(N / 128, M / 128, batch * ksplit);
    if (bt) mfma_gemm<true ><<<g, blk, 0, stream>>>(A, lda, a_hi, a_lo, Bp, ldb, b_hi, b_lo,
                                                    Cp, ldc, c_hi, c_lo, pstride, M, N, K, nh, ksplit, scale, bias);
    else    mfma_gemm<false><<<g, blk, 0, stream>>>(A, lda, a_hi, a_lo, Bp, ldb, b_hi, b_lo,
                                                    Cp, ldc, c_hi, c_lo, pstride, M, N, K, nh, ksplit, scale, bias);
  };

  auto attention = [&](const float* qsrc, const float* kvsrc,
                       const float* qkvw, const float* qkvb,
                       const float* ow, const float* ob, int causal) {
    // QKV projections (N-mode weights [D][HD])
    gemm(false, qsrc,  D_, 0, 0, qkvw + 0 * (size_t)D_ * HD_, HD_, 0, 0,
         Qb, HD_, 0, 0, 0, BT_, HD_, D_, 1, 1, 1, 1.0f, qkvb + 0 * HD_);
    gemm(false, kvsrc, D_, 0, 0, qkvw + 1 * (size_t)D_ * HD_, HD_, 0, 0,
         Kb, HD_, 0, 0, 0, BT_, HD_, D_, 1, 1, 1, 1.0f, qkvb + 1 * HD_);
    gemm(false, kvsrc, D_, 0, 0, qkvw + 2 * (size_t)D_ * HD_, HD_, 0, 0,
         Vb, HD_, 0, 0, 0, BT_, HD_, D_, 1, 1, 1, 1.0f, qkvb + 2 * HD_);
    // S = Q K^T / sqrt(D)  (BT-mode, batched over 16 bh)
    gemm(true, Qb, HD_, THD, D_, Kb, HD_, THD, D_,
         Sb, T_, (long)H_ * TT, TT, 0, T_, T_, D_, BH_, H_, 1,
         0.044194173824159216f, nullptr);
    softmax_kernel<<<dim3(T_, BH_), blk, 0, stream>>>(Sb, causal);
    // O = P V  (N-mode, batched)
    gemm(false, Sb, T_, (long)H_ * TT, TT, Vb, HD_, THD, D_,
         Ob, HD_, THD, D_, 0, T_, D_, T_, BH_, H_, 1, 1.0f, nullptr);
    // out-projection, split-K=8 -> partial in Sb, then reduce+bias -> aa
    gemm(false, Ob, HD_, 0, 0, ow, D_, 0, 0,
         Sb, D_, 0, 0, (long)BT_ * D_, BT_, D_, HD_, 1, 1, 8, 1.0f, nullptr);
    reduce_bias_kernel<<<dim3(BT_ * D_ / 1024), blk, 0, stream>>>(
        Sb, (long)BT_ * D_, 8, ob, 0, aa, (long)BT_ * D_, D_);
  };

  auto ffn = [&](float* act, const float* w1, const float* b1,
                 const float* w2, const float* b2) {
    gemm(false, act, D_, 0, 0, w1, F_, 0, 0,
         Sb, F_, 0, 0, (long)BT_ * F_, BT_, F_, D_, 1, 1, 2, 1.0f, nullptr);
    reduce_bias_kernel<<<dim3(BT_ * F_ / 1024), blk, 0, stream>>>(
        Sb, (long)BT_ * F_, 2, b1, 1, mid, (long)BT_ * F_, F_);
    gemm(false, mid, F_, 0, 0, w2, D_, 0, 0,
         Sb, D_, 0, 0, (long)BT_ * D_, BT_, D_, F_, 1, 1, 8, 1.0f, nullptr);
    reduce_bias_kernel<<<dim3(BT_ * D_ / 1024), blk, 0, stream>>>(
        Sb, (long)BT_ * D_, 8, b2, 0, aa, (long)BT_ * D_, D_);
  };

  auto add_ln = [&](const float* a_, float* h_, const float* g_, const float* b_) {
    add_ln_kernel<<<dim3(BT_), blk, 0, stream>>>(a_, h_, g_, b_);
  };

  // ---------------- encoder ----------------
  embed_kernel<<<dim3(BT_), blk, 0, stream>>>(x, enc_emb, h);
  for (int i = 0; i < L_; ++i) {
    attention(h, h,
              enc_qkv_w + (size_t)i * 3 * D_ * HD_, enc_qkv_b + (size_t)i * 3 * HD_,
              enc_out_w + (size_t)i * HD_ * D_, enc_out_b + (size_t)i * D_, 0);
    add_ln(aa, h, enc_ln1_g + (size_t)i * D_, enc_ln1_b + (size_t)i * D_);
    ffn(h, enc_ff_w1 + (size_t)i * D_ * F_, enc_ff_b1 + (size_t)i * F_,
        enc_ff_w2 + (size_t)i * F_ * D_, enc_ff_b2 + (size_t)i * D_);
    add_ln(aa, h, enc_ln2_g + (size_t)i * D_, enc_ln2_b + (size_t)i * D_);
  }

  // ---------------- decoder ----------------
  embed_kernel<<<dim3(BT_), blk, 0, stream>>>(y, dec_emb, dd);
  for (int i = 0; i < L_; ++i) {
    attention(dd, dd,
              dec_sa_qkv_w + (size_t)i * 3 * D_ * HD_, dec_sa_qkv_b + (size_t)i * 3 * HD_,
              dec_sa_out_w + (size_t)i * HD_ * D_, dec_sa_out_b + (size_t)i * D_, 1);
    add_ln(aa, dd, dec_ln1_g + (size_t)i * D_, dec_ln1_b + (size_t)i * D_);
    attention(dd, h,
              dec_ca_qkv_w + (size_t)i * 3 * D_ * HD_, dec_ca_qkv_b + (size_t)i * 3 * HD_,
              dec_ca_out_w + (size_t)i * HD_ * D_, dec_ca_out_b + (size_t)i * D_, 0);
    add_ln(aa, dd, dec_ln2_g + (size_t)i * D_, dec_ln2_b + (size_t)i * D_);
    ffn(dd, dec_ff_w1 + (size_t)i * D_ * F_, dec_ff_b1 + (size_t)i * F_,
        dec_ff_w2 + (size_t)i * F_ * D_, dec_ff_b2 + (size_t)i * D_);
    add_ln(aa, dd, dec_ln3_g + (size_t)i * D_, dec_ln3_b + (size_t)i * D_);
  }

  // ---------------- LM head -> f32 logits ----------------
  gemm(false, dd, D_, 0, 0, head_w, V_, 0, 0,
       out, V_, 0, 0, 0, BT_, V_, D_, 1, 1, 1, 1.0f, head_b);
}

// Round 4
// 2978.854 us; speedup vs baseline: 4.6723x; 1.3406x over previous
//
#include <hip/hip_runtime.h>
#include <hip/hip_bf16.h>

#define B_ 2
#define T_ 512
#define D_ 512
#define H_ 8
#define L_ 6
#define F_ 2048
#define V_ 32000
#define BT_ (B_ * T_)
#define HD_ (H_ * D_)
#define BH_ (B_ * H_)

typedef __attribute__((ext_vector_type(8))) short short8;
typedef __attribute__((ext_vector_type(4))) float f32x4;

__device__ __forceinline__ short f2b(float f) {
  __hip_bfloat16 h = __float2bfloat16(f);
  short u; __builtin_memcpy(&u, &h, 2); return u;
}

// ---------------- embedding * sqrt(D) + sinusoidal PE ----------------
__global__ __launch_bounds__(256) void embed_kernel(
    const int* __restrict__ tok, const float* __restrict__ emb, float* __restrict__ out)
{
  const int row = blockIdx.x;            // b*T + t
  const int t = row & (T_ - 1);
  const int token = tok[row];
  const float* e = emb + (size_t)token * D_;
  float* o = out + (size_t)row * D_;
  const float scale = sqrtf((float)D_);
  const float nl = -logf(10000.0f);
  for (int d = threadIdx.x; d < D_; d += 256) {
    int i = d >> 1;
    float wl = expf(nl * (2.0f * (float)i) / (float)D_);
    float ang = (float)t * wl;
    float pe = (d & 1) ? cosf(ang) : sinf(ang);
    o[d] = e[d] * scale + pe;
  }
}

// ---------------- generic bf16-MFMA GEMM, double-buffered ----------------
// C[M,N] = (A[M,K](f32) @ B(f32)) * scale (+bias); BTM: B stored [N][K].
// 128x128 tile, BK=64, 4 waves. z = batch(nh sub-batches) x ksplit.
// LDS chunk-major [chunk=k/8][row][8 bf16], chunk stride 129 (bank-spread).
template<bool BTM>
__global__ __launch_bounds__(256) void mfma_gemm(
    const float* __restrict__ A, long lda, long a_hi, long a_lo,
    const float* __restrict__ B, long ldb, long b_hi, long b_lo,
    float* __restrict__ C, long ldc, long c_hi, long c_lo, long pstride,
    int K, int nh, int ksplit, float scale,
    const float* __restrict__ bias, long bias_stride)
{
  __shared__ short8 As8[2][8 * 129];
  __shared__ short8 Bs8[2][8 * 129];
  const int tid = threadIdx.x;
  const int bh = blockIdx.z / ksplit;
  const int kz = blockIdx.z - bh * ksplit;
  const int bb = bh / nh, hh = bh - bb * nh;
  const float* Ab = A + (long)bb * a_hi + (long)hh * a_lo;
  const float* Bb = B + (long)bb * b_hi + (long)hh * b_lo;
  float* Cb = C + (long)bb * c_hi + (long)hh * c_lo + (long)kz * pstride;

  // XCD-chunked bijective swizzle; y-major decomposition so the blocks
  // sharing a B(N-)panel are contiguous on one XCD's L2.
  const int gx = gridDim.x, gy = gridDim.y;
  const int nwg = gx * gy;
  int lin = blockIdx.y * gx + blockIdx.x;
  {
    const int xcd = lin & 7, idx = lin >> 3;
    const int q = nwg >> 3, r = nwg & 7;
    lin = (xcd < r ? xcd * (q + 1) : r * (q + 1) + (xcd - r) * q) + idx;
  }
  const int bn = (lin / gy) * 128;
  const int bm = (lin % gy) * 128;

  const int klen = K / ksplit, kbase = kz * klen;
  const int lane = tid & 63, wid = tid >> 6;
  const int wr = wid >> 1, wc = wid & 1;
  const int lg = lane >> 4, r16 = lane & 15;

  int arow[4], acol[4];
#pragma unroll
  for (int u = 0; u < 4; ++u) { int o = u * 256 + tid; arow[u] = o >> 3; acol[u] = o & 7; }
  const int ncol = tid & 127, nsh = tid >> 7;

  float4 pa[4][2];
  float4 pbt[4][2];
  float  pbn[4][8];

  auto load_a = [&](int k0) {
#pragma unroll
    for (int u = 0; u < 4; ++u) {
      const float* s = Ab + (long)(bm + arow[u]) * lda + (k0 + acol[u] * 8);
      pa[u][0] = *(const float4*)(s);
      pa[u][1] = *(const float4*)(s + 4);
    }
  };
  auto load_b = [&](int k0) {
    if constexpr (BTM) {
#pragma unroll
      for (int u = 0; u < 4; ++u) {
        const float* s = Bb + (long)(bn + arow[u]) * ldb + (k0 + acol[u] * 8);
        pbt[u][0] = *(const float4*)(s);
        pbt[u][1] = *(const float4*)(s + 4);
      }
    } else {
      const float* s = Bb + (long)(k0 + nsh * 32) * ldb + (bn + ncol);
#pragma unroll
      for (int i = 0; i < 4; ++i)
#pragma unroll
        for (int j = 0; j < 8; ++j)
          pbn[i][j] = s[(long)(i * 8 + j) * ldb];
    }
  };
  auto stage = [&](int bf) {
#pragma unroll
    for (int u = 0; u < 4; ++u) {
      short8 v;
      v[0] = f2b(pa[u][0].x); v[1] = f2b(pa[u][0].y); v[2] = f2b(pa[u][0].z); v[3] = f2b(pa[u][0].w);
      v[4] = f2b(pa[u][1].x); v[5] = f2b(pa[u][1].y); v[6] = f2b(pa[u][1].z); v[7] = f2b(pa[u][1].w);
      As8[bf][acol[u] * 129 + arow[u]] = v;
    }
    if constexpr (BTM) {
#pragma unroll
      for (int u = 0; u < 4; ++u) {
        short8 v;
        v[0] = f2b(pbt[u][0].x); v[1] = f2b(pbt[u][0].y); v[2] = f2b(pbt[u][0].z); v[3] = f2b(pbt[u][0].w);
        v[4] = f2b(pbt[u][1].x); v[5] = f2b(pbt[u][1].y); v[6] = f2b(pbt[u][1].z); v[7] = f2b(pbt[u][1].w);
        Bs8[bf][acol[u] * 129 + arow[u]] = v;
      }
    } else {
#pragma unroll
      for (int i = 0; i < 4; ++i) {
        short8 v;
#pragma unroll
        for (int j = 0; j < 8; ++j) v[j] = f2b(pbn[i][j]);
        Bs8[bf][(nsh * 4 + i) * 129 + ncol] = v;
      }
    }
  };

  f32x4 acc[4][4] = {};
  auto domfma = [&](int bf) {
#pragma unroll
    for (int kb = 0; kb < 2; ++kb) {
      const int ch = (kb * 4 + lg) * 129;
      short8 a0 = As8[bf][ch + wr * 64 +  0 + r16];
      short8 a1 = As8[bf][ch + wr * 64 + 16 + r16];
      short8 a2 = As8[bf][ch + wr * 64 + 32 + r16];
      short8 a3 = As8[bf][ch + wr * 64 + 48 + r16];
#pragma unroll
      for (int n = 0; n < 4; ++n) {
        short8 bfr = Bs8[bf][ch + wc * 64 + n * 16 + r16];
        acc[0][n] = __builtin_amdgcn_mfma_f32_16x16x32_bf16(a0, bfr, acc[0][n], 0, 0, 0);
        acc[1][n] = __builtin_amdgcn_mfma_f32_16x16x32_bf16(a1, bfr, acc[1][n], 0, 0, 0);
        acc[2][n] = __builtin_amdgcn_mfma_f32_16x16x32_bf16(a2, bfr, acc[2][n], 0, 0, 0);
        acc[3][n] = __builtin_amdgcn_mfma_f32_16x16x32_bf16(a3, bfr, acc[3][n], 0, 0, 0);
      }
    }
  };

  load_a(kbase); load_b(kbase);
  stage(0);
  __syncthreads();
  const int nsteps = klen >> 6;   // always even (>=4) for our shapes
  for (int t = 0; t < nsteps; ++t) {
    const int cur = t & 1;
    if (t + 1 < nsteps) { load_a(kbase + (t + 1) * 64); load_b(kbase + (t + 1) * 64); }
    domfma(cur);                         // no dep on in-flight loads
    if (t + 1 < nsteps) stage(cur ^ 1);  // waitcnt lands here, after MFMA
    __syncthreads();
  }

  const float* bp = bias ? bias + (long)hh * bias_stride : nullptr;
#pragma unroll
  for (int m = 0; m < 4; ++m)
#pragma unroll
    for (int rr = 0; rr < 4; ++rr) {
      const int row = bm + wr * 64 + m * 16 + lg * 4 + rr;
      float* crow = Cb + (long)row * ldc + bn + wc * 64 + r16;
#pragma unroll
      for (int n = 0; n < 4; ++n) {
        float v = acc[m][n][rr] * scale;
        if (bp) v += bp[bn + wc * 64 + n * 16 + r16];
        crow[n * 16] = v;
      }
    }
}

// ---------------- split-K reduce: out = (sum_z partial + bias), opt relu ----------------
__global__ __launch_bounds__(256) void reduce_bias_kernel(
    const float* __restrict__ P, long pstride, int ks,
    const float* __restrict__ bias, int relu,
    float* __restrict__ out, long mn, int N)
{
  const long i = ((long)blockIdx.x * 256 + threadIdx.x) * 4;
  if (i >= mn) return;
  float4 s = *(const float4*)(P + i);
  for (int z = 1; z < ks; ++z) {
    float4 t = *(const float4*)(P + (long)z * pstride + i);
    s.x += t.x; s.y += t.y; s.z += t.z; s.w += t.w;
  }
  const int col = (int)(i % N);
  s.x += bias[col]; s.y += bias[col + 1]; s.z += bias[col + 2]; s.w += bias[col + 3];
  if (relu) {
    s.x = fmaxf(s.x, 0.f); s.y = fmaxf(s.y, 0.f);
    s.z = fmaxf(s.z, 0.f); s.w = fmaxf(s.w, 0.f);
  }
  *(float4*)(out + i) = s;
}

// ---------------- fused: x = resid + bias + sum_z partial; resid = LN(x)*g+b ----------------
__global__ __launch_bounds__(256) void reduce_ln_kernel(
    const float* __restrict__ P, long pstride, int ks,
    const float* __restrict__ bias, float* __restrict__ hbuf,
    const float* __restrict__ gam, const float* __restrict__ bet)
{
  __shared__ float red[256];
  const int row = blockIdx.x, tid = threadIdx.x;
  const long base = (long)row * D_;
  float s0 = hbuf[base + tid] + bias[tid];
  float s1 = hbuf[base + tid + 256] + bias[tid + 256];
  for (int z = 0; z < ks; ++z) {
    s0 += P[(long)z * pstride + base + tid];
    s1 += P[(long)z * pstride + base + tid + 256];
  }
  red[tid] = s0 + s1; __syncthreads();
  for (int o = 128; o > 0; o >>= 1) { if (tid < o) red[tid] += red[tid + o]; __syncthreads(); }
  const float mean = red[0] * (1.0f / D_); __syncthreads();
  const float d0 = s0 - mean, d1 = s1 - mean;
  red[tid] = d0 * d0 + d1 * d1; __syncthreads();
  for (int o = 128; o > 0; o >>= 1) { if (tid < o) red[tid] += red[tid + o]; __syncthreads(); }
  const float inv = rsqrtf(red[0] * (1.0f / D_) + 1e-6f);
  hbuf[base + tid]       = d0 * inv * gam[tid]       + bet[tid];
  hbuf[base + tid + 256] = d1 * inv * gam[tid + 256] + bet[tid + 256];
}

// ---------------- single-pass row softmax; causal k<=q; masked tail -> 0 ----------------
__global__ __launch_bounds__(256) void softmax_kernel(float* __restrict__ S, int causal)
{
  __shared__ float red[256];
  const int q = blockIdx.x, bh = blockIdx.y, tid = threadIdx.x;
  float* row = S + ((size_t)bh * T_ + q) * T_;
  const int n = causal ? (q + 1) : T_;
  const float v0 = row[tid], v1 = row[tid + 256];
  const bool in0 = tid < n, in1 = (tid + 256) < n;
  red[tid] = fmaxf(in0 ? v0 : -3.0e38f, in1 ? v1 : -3.0e38f);
  __syncthreads();
  for (int o = 128; o > 0; o >>= 1) { if (tid < o) red[tid] = fmaxf(red[tid], red[tid + o]); __syncthreads(); }
  const float m = red[0]; __syncthreads();
  const float e0 = in0 ? expf(v0 - m) : 0.0f;
  const float e1 = in1 ? expf(v1 - m) : 0.0f;
  red[tid] = e0 + e1; __syncthreads();
  for (int o = 128; o > 0; o >>= 1) { if (tid < o) red[tid] += red[tid + o]; __syncthreads(); }
  const float inv = 1.0f / red[0];
  row[tid] = e0 * inv;
  row[tid + 256] = e1 * inv;
}

extern "C" void kernel_launch(void* const* d_in, const int* in_sizes, int n_in,
                              void* d_out, int out_size, void* d_ws, size_t ws_size,
                              hipStream_t stream)
{
  const int*   x         = (const int*)d_in[0];
  const int*   y         = (const int*)d_in[1];
  const float* enc_emb   = (const float*)d_in[2];
  const float* dec_emb   = (const float*)d_in[3];
  const float* enc_qkv_w = (const float*)d_in[4];
  const float* enc_qkv_b = (const float*)d_in[5];
  const float* enc_out_w = (const float*)d_in[6];
  const float* enc_out_b = (const float*)d_in[7];
  const float* enc_ln1_g = (const float*)d_in[8];
  const float* enc_ln1_b = (const float*)d_in[9];
  const float* enc_ff_w1 = (const float*)d_in[10];
  const float* enc_ff_b1 = (const float*)d_in[11];
  const float* enc_ff_w2 = (const float*)d_in[12];
  const float* enc_ff_b2 = (const float*)d_in[13];
  const float* enc_ln2_g = (const float*)d_in[14];
  const float* enc_ln2_b = (const float*)d_in[15];
  const float* dec_sa_qkv_w = (const float*)d_in[16];
  const float* dec_sa_qkv_b = (const float*)d_in[17];
  const float* dec_sa_out_w = (const float*)d_in[18];
  const float* dec_sa_out_b = (const float*)d_in[19];
  const float* dec_ln1_g = (const float*)d_in[20];
  const float* dec_ln1_b = (const float*)d_in[21];
  const float* dec_ca_qkv_w = (const float*)d_in[22];
  const float* dec_ca_qkv_b = (const float*)d_in[23];
  const float* dec_ca_out_w = (const float*)d_in[24];
  const float* dec_ca_out_b = (const float*)d_in[25];
  const float* dec_ln2_g = (const float*)d_in[26];
  const float* dec_ln2_b = (const float*)d_in[27];
  const float* dec_ff_w1 = (const float*)d_in[28];
  const float* dec_ff_b1 = (const float*)d_in[29];
  const float* dec_ff_w2 = (const float*)d_in[30];
  const float* dec_ff_b2 = (const float*)d_in[31];
  const float* dec_ln3_g = (const float*)d_in[32];
  const float* dec_ln3_b = (const float*)d_in[33];
  const float* head_w    = (const float*)d_in[34];
  const float* head_b    = (const float*)d_in[35];
  float* out = (float*)d_out;

  // workspace (fp32): h, dd, Q/K/V (contiguous!), S (doubles as split-K partials)
  float* ws = (float*)d_ws;
  size_t off = 0;
  float* h  = ws + off; off += (size_t)BT_ * D_;
  float* dd = ws + off; off += (size_t)BT_ * D_;
  float* Qb = ws + off; off += (size_t)BT_ * HD_;
  float* Kb = ws + off; off += (size_t)BT_ * HD_;
  float* Vb = ws + off; off += (size_t)BT_ * HD_;
  float* Sb = ws + off; off += (size_t)BH_ * T_ * T_;
  float* Ob  = Qb;   // Q dead after qk
  float* mid = Qb;   // attn buffers dead during FFN

  dim3 blk(256);
  const long TT  = (long)T_ * T_;
  const long THD = (long)T_ * HD_;
  const long WQKV = (long)D_ * HD_;

  auto gemm = [&](bool bt, const float* A, long lda, long a_hi, long a_lo,
                  const float* Bp, long ldb, long b_hi, long b_lo,
                  float* Cp, long ldc, long c_hi, long c_lo, long pstride,
                  int M, int N, int K, int batch, int nh, int ksplit,
                  float scale, const float* bias, long bstride) {
    dim3 grd(N / 128, M / 128, batch * ksplit);
    if (bt) mfma_gemm<true ><<<grd, blk, 0, stream>>>(A, lda, a_hi, a_lo, Bp, ldb, b_hi, b_lo,
                 Cp, ldc, c_hi, c_lo, pstride, K, nh, ksplit, scale, bias, bstride);
    else    mfma_gemm<false><<<grd, blk, 0, stream>>>(A, lda, a_hi, a_lo, Bp, ldb, b_hi, b_lo,
                 Cp, ldc, c_hi, c_lo, pstride, K, nh, ksplit, scale, bias, bstride);
  };

  auto attention = [&](const float* qsrc, const float* kvsrc, bool self,
                       const float* qkvw, const float* qkvb,
                       const float* ow, const float* ob, float* resid, int causal,
                       const float* lng, const float* lnb) {
    if (self) {
      // fused Q,K,V in one dispatch (batch z=3 over weight/bias/output)
      gemm(false, qsrc, D_, 0, 0, qkvw, HD_, 0, WQKV,
           Qb, HD_, 0, (long)BT_ * HD_, 0, BT_, HD_, D_, 3, 3, 1, 1.0f, qkvb, HD_);
    } else {
      gemm(false, qsrc, D_, 0, 0, qkvw, HD_, 0, 0,
           Qb, HD_, 0, 0, 0, BT_, HD_, D_, 1, 1, 1, 1.0f, qkvb, 0);
      gemm(false, kvsrc, D_, 0, 0, qkvw + WQKV, HD_, 0, WQKV,
           Kb, HD_, 0, (long)BT_ * HD_, 0, BT_, HD_, D_, 2, 2, 1, 1.0f, qkvb + HD_, HD_);
    }
    gemm(true, Qb, HD_, THD, D_, Kb, HD_, THD, D_,
         Sb, T_, (long)H_ * TT, TT, 0, T_, T_, D_, BH_, H_, 1,
         0.044194173824159216f, nullptr, 0);
    softmax_kernel<<<dim3(T_, BH_), blk, 0, stream>>>(Sb, causal);
    gemm(false, Sb, T_, (long)H_ * TT, TT, Vb, HD_, THD, D_,
         Ob, HD_, THD, D_, 0, T_, D_, T_, BH_, H_, 1, 1.0f, nullptr, 0);
    // out-projection split-K=8 -> partials in Sb, fused reduce+bias+residual+LN
    gemm(false, Ob, HD_, 0, 0, ow, D_, 0, 0,
         Sb, D_, 0, 0, (long)BT_ * D_, BT_, D_, HD_, 1, 1, 8, 1.0f, nullptr, 0);
    reduce_ln_kernel<<<dim3(BT_), blk, 0, stream>>>(
        Sb, (long)BT_ * D_, 8, ob, resid, lng, lnb);
  };

  auto ffn = [&](float* resid, const float* w1, const float* b1,
                 const float* w2, const float* b2,
                 const float* lng, const float* lnb) {
    gemm(false, resid, D_, 0, 0, w1, F_, 0, 0,
         Sb, F_, 0, 0, (long)BT_ * F_, BT_, F_, D_, 1, 1, 2, 1.0f, nullptr, 0);
    reduce_bias_kernel<<<dim3(BT_ * F_ / 1024), blk, 0, stream>>>(
        Sb, (long)BT_ * F_, 2, b1, 1, mid, (long)BT_ * F_, F_);
    gemm(false, mid, F_, 0, 0, w2, D_, 0, 0,
         Sb, D_, 0, 0, (long)BT_ * D_, BT_, D_, F_, 1, 1, 8, 1.0f, nullptr, 0);
    reduce_ln_kernel<<<dim3(BT_), blk, 0, stream>>>(
        Sb, (long)BT_ * D_, 8, b2, resid, lng, lnb);
  };

  // ---------------- encoder ----------------
  embed_kernel<<<dim3(BT_), blk, 0, stream>>>(x, enc_emb, h);
  for (int i = 0; i < L_; ++i) {
    attention(h, h, true,
              enc_qkv_w + (size_t)i * 3 * WQKV, enc_qkv_b + (size_t)i * 3 * HD_,
              enc_out_w + (size_t)i * HD_ * D_, enc_out_b + (size_t)i * D_,
              h, 0, enc_ln1_g + (size_t)i * D_, enc_ln1_b + (size_t)i * D_);
    ffn(h, enc_ff_w1 + (size_t)i * D_ * F_, enc_ff_b1 + (size_t)i * F_,
        enc_ff_w2 + (size_t)i * F_ * D_, enc_ff_b2 + (size_t)i * D_,
        enc_ln2_g + (size_t)i * D_, enc_ln2_b + (size_t)i * D_);
  }

  // ---------------- decoder ----------------
  embed_kernel<<<dim3(BT_), blk, 0, stream>>>(y, dec_emb, dd);
  for (int i = 0; i < L_; ++i) {
    attention(dd, dd, true,
              dec_sa_qkv_w + (size_t)i * 3 * WQKV, dec_sa_qkv_b + (size_t)i * 3 * HD_,
              dec_sa_out_w + (size_t)i * HD_ * D_, dec_sa_out_b + (size_t)i * D_,
              dd, 1, dec_ln1_g + (size_t)i * D_, dec_ln1_b + (size_t)i * D_);
    attention(dd, h, false,
              dec_ca_qkv_w + (size_t)i * 3 * WQKV, dec_ca_qkv_b + (size_t)i * 3 * HD_,
              dec_ca_out_w + (size_t)i * HD_ * D_, dec_ca_out_b + (size_t)i * D_,
              dd, 0, dec_ln2_g + (size_t)i * D_, dec_ln2_b + (size_t)i * D_);
    ffn(dd, dec_ff_w1 + (size_t)i * D_ * F_, dec_ff_b1 + (size_t)i * F_,
        dec_ff_w2 + (size_t)i * F_ * D_, dec_ff_b2 + (size_t)i * D_,
        dec_ln3_g + (size_t)i * D_, dec_ln3_b + (size_t)i * D_);
  }

  // ---------------- LM head -> f32 logits ----------------
  gemm(false, dd, D_, 0, 0, head_w, V_, 0, 0,
       out, V_, 0, 0, 0, BT_, V_, D_, 1, 1, 1, 1.0f, head_b, 0);
}

// Round 5
// 2402.588 us; speedup vs baseline: 5.7930x; 1.2399x over previous
//
#include <hip/hip_runtime.h>
#include <hip/hip_bf16.h>

#define B_ 2
#define T_ 512
#define D_ 512
#define H_ 8
#define L_ 6
#define F_ 2048
#define V_ 32000
#define BT_ (B_ * T_)
#define HD_ (H_ * D_)
#define BH_ (B_ * H_)

typedef __attribute__((ext_vector_type(8))) short short8;
typedef __attribute__((ext_vector_type(4))) short short4v;
typedef __attribute__((ext_vector_type(4))) float f32x4;

__device__ __forceinline__ short f2b(float f) {
  __hip_bfloat16 h = __float2bfloat16(f);
  short u; __builtin_memcpy(&u, &h, 2); return u;
}
__device__ __forceinline__ void store_c(float* p, float v) { *p = v; }
__device__ __forceinline__ void store_c(short* p, float v) { *p = f2b(v); }

// ---------------- embedding * sqrt(D) + sinusoidal PE (f32 + bf16 copies) ----------------
__global__ __launch_bounds__(256) void embed_kernel(
    const int* __restrict__ tok, const float* __restrict__ emb,
    float* __restrict__ out, short* __restrict__ out16)
{
  const int row = blockIdx.x;            // b*T + t
  const int t = row & (T_ - 1);
  const int token = tok[row];
  const float* e = emb + (size_t)token * D_;
  float* o = out + (size_t)row * D_;
  short* o16 = out16 + (size_t)row * D_;
  const float scale = sqrtf((float)D_);
  const float nl = -logf(10000.0f);
  for (int d = threadIdx.x; d < D_; d += 256) {
    int i = d >> 1;
    float wl = expf(nl * (2.0f * (float)i) / (float)D_);
    float ang = (float)t * wl;
    float pe = (d & 1) ? cosf(ang) : sinf(ang);
    float v = e[d] * scale + pe;
    o[d] = v; o16[d] = f2b(v);
  }
}

// ---------------- generic MFMA GEMM ----------------
// A: bf16 [.,K] rows k-contig. B: BTM ? bf16 [N][K] (k-contig) : f32 [K][N] weights.
// C: OutT (f32/bf16). Optional transposed bf16 store (sub-batch hh==trans_hh) to
// Ct[col*BT_ + row] (used to produce V^T). 128x128 tile, BK=64, 4 waves,
// single-buffer LDS + reg prefetch. z = batch(nh) x ksplit.
template<bool BTM, typename OutT>
__global__ __launch_bounds__(256, 3) void mfma_gemm(
    const short* __restrict__ A, long lda, long a_hi, long a_lo,
    const void* __restrict__ Bv, long ldb, long b_hi, long b_lo,
    OutT* __restrict__ C, long ldc, long c_hi, long c_lo, long pstride,
    short* __restrict__ Ct, int trans_hh,
    int K, int nh, int ksplit, float scale,
    const float* __restrict__ bias, long bias_stride)
{
  __shared__ short8 As8[8 * 129];
  __shared__ short8 Bs8[8 * 129];
  const int tid = threadIdx.x;
  const int bh = blockIdx.z / ksplit;
  const int kz = blockIdx.z - bh * ksplit;
  const int bb = bh / nh, hh = bh - bb * nh;
  const short* Ab = A + (long)bb * a_hi + (long)hh * a_lo;
  const short* Bbs = (const short*)Bv + (long)bb * b_hi + (long)hh * b_lo;
  const float* Bbf = (const float*)Bv + (long)bb * b_hi + (long)hh * b_lo;
  OutT* Cb = C + (long)bb * c_hi + (long)hh * c_lo + (long)kz * pstride;

  // XCD-chunked bijective swizzle, y-major (same-N-panel blocks share an XCD L2)
  const int gx = gridDim.x, gy = gridDim.y;
  const int nwg = gx * gy;
  int lin = blockIdx.y * gx + blockIdx.x;
  {
    const int xcd = lin & 7, idx = lin >> 3;
    const int q = nwg >> 3, r = nwg & 7;
    lin = (xcd < r ? xcd * (q + 1) : r * (q + 1) + (xcd - r) * q) + idx;
  }
  const int bn = (lin / gy) * 128;
  const int bm = (lin % gy) * 128;

  const int klen = K / ksplit, kbase = kz * klen;
  const int lane = tid & 63, wid = tid >> 6;
  const int wr = wid >> 1, wc = wid & 1;
  const int lg = lane >> 4, r16 = lane & 15;

  int arow[4], acol[4];
#pragma unroll
  for (int u = 0; u < 4; ++u) { int o = u * 256 + tid; arow[u] = o >> 3; acol[u] = o & 7; }
  const int ncol = tid & 127, nsh = tid >> 7;

  short8 pa[4];
  short8 pbt[4];
  float  pbn[4][8];

  auto load = [&](int k0) {
#pragma unroll
    for (int u = 0; u < 4; ++u)
      pa[u] = *(const short8*)(Ab + (long)(bm + arow[u]) * lda + (k0 + acol[u] * 8));
    if constexpr (BTM) {
#pragma unroll
      for (int u = 0; u < 4; ++u)
        pbt[u] = *(const short8*)(Bbs + (long)(bn + arow[u]) * ldb + (k0 + acol[u] * 8));
    } else {
      const float* s = Bbf + (long)(k0 + nsh * 32) * ldb + (bn + ncol);
#pragma unroll
      for (int i = 0; i < 4; ++i)
#pragma unroll
        for (int j = 0; j < 8; ++j)
          pbn[i][j] = s[(long)(i * 8 + j) * ldb];
    }
  };
  auto stage = [&]() {
#pragma unroll
    for (int u = 0; u < 4; ++u) As8[acol[u] * 129 + arow[u]] = pa[u];
    if constexpr (BTM) {
#pragma unroll
      for (int u = 0; u < 4; ++u) Bs8[acol[u] * 129 + arow[u]] = pbt[u];
    } else {
#pragma unroll
      for (int i = 0; i < 4; ++i) {
        short8 v;
#pragma unroll
        for (int j = 0; j < 8; ++j) v[j] = f2b(pbn[i][j]);
        Bs8[(nsh * 4 + i) * 129 + ncol] = v;
      }
    }
  };

  f32x4 acc[4][4] = {};
  auto domfma = [&]() {
#pragma unroll
    for (int kb = 0; kb < 2; ++kb) {
      const int ch = (kb * 4 + lg) * 129;
      short8 a0 = As8[ch + wr * 64 +  0 + r16];
      short8 a1 = As8[ch + wr * 64 + 16 + r16];
      short8 a2 = As8[ch + wr * 64 + 32 + r16];
      short8 a3 = As8[ch + wr * 64 + 48 + r16];
#pragma unroll
      for (int n = 0; n < 4; ++n) {
        short8 bfr = Bs8[ch + wc * 64 + n * 16 + r16];
        acc[0][n] = __builtin_amdgcn_mfma_f32_16x16x32_bf16(a0, bfr, acc[0][n], 0, 0, 0);
        acc[1][n] = __builtin_amdgcn_mfma_f32_16x16x32_bf16(a1, bfr, acc[1][n], 0, 0, 0);
        acc[2][n] = __builtin_amdgcn_mfma_f32_16x16x32_bf16(a2, bfr, acc[2][n], 0, 0, 0);
        acc[3][n] = __builtin_amdgcn_mfma_f32_16x16x32_bf16(a3, bfr, acc[3][n], 0, 0, 0);
      }
    }
  };

  load(kbase);
  stage();
  __syncthreads();
  const int nsteps = klen >> 6;
  for (int t = 0; t < nsteps; ++t) {
    const bool more = (t + 1 < nsteps);
    if (more) load(kbase + (t + 1) * 64);
    domfma();
    if (more) { __syncthreads(); stage(); __syncthreads(); }
  }

  const float* bp = bias ? bias + (long)hh * bias_stride : nullptr;
  if (hh == trans_hh) {
    // transposed bf16 store: Ct[col][row], col = feature, row = token
#pragma unroll
    for (int m = 0; m < 4; ++m)
#pragma unroll
      for (int n = 0; n < 4; ++n) {
        const int col = bn + wc * 64 + n * 16 + r16;
        const float badd = bp ? bp[col] : 0.0f;
        short4v sv;
#pragma unroll
        for (int rr = 0; rr < 4; ++rr) sv[rr] = f2b(acc[m][n][rr] * scale + badd);
        *(short4v*)(Ct + (long)col * BT_ + (bm + wr * 64 + m * 16 + lg * 4)) = sv;
      }
  } else {
#pragma unroll
    for (int m = 0; m < 4; ++m)
#pragma unroll
      for (int rr = 0; rr < 4; ++rr) {
        const int row = bm + wr * 64 + m * 16 + lg * 4 + rr;
        OutT* crow = Cb + (long)row * ldc + bn + wc * 64 + r16;
#pragma unroll
        for (int n = 0; n < 4; ++n) {
          float v = acc[m][n][rr] * scale;
          if (bp) v += bp[bn + wc * 64 + n * 16 + r16];
          store_c(&crow[n * 16], v);
        }
      }
  }
}

// ---------------- split-K reduce + bias + relu -> bf16 (FFN mid) ----------------
__global__ __launch_bounds__(256) void reduce_bias_relu_bf16(
    const float* __restrict__ P, long pstride, int ks,
    const float* __restrict__ bias, short* __restrict__ out, long mn, int N)
{
  const long i = ((long)blockIdx.x * 256 + threadIdx.x) * 4;
  if (i >= mn) return;
  float4 s = *(const float4*)(P + i);
  for (int z = 1; z < ks; ++z) {
    float4 t = *(const float4*)(P + (long)z * pstride + i);
    s.x += t.x; s.y += t.y; s.z += t.z; s.w += t.w;
  }
  const int col = (int)(i % N);
  s.x += bias[col]; s.y += bias[col + 1]; s.z += bias[col + 2]; s.w += bias[col + 3];
  short4v o;
  o[0] = f2b(fmaxf(s.x, 0.f)); o[1] = f2b(fmaxf(s.y, 0.f));
  o[2] = f2b(fmaxf(s.z, 0.f)); o[3] = f2b(fmaxf(s.w, 0.f));
  *(short4v*)(out + i) = o;
}

// ---- fused: x = resid + bias + sum_z partial; resid(f32) = LN(x)*g+b; + bf16 copy ----
__global__ __launch_bounds__(256) void reduce_ln_kernel(
    const float* __restrict__ P, long pstride, int ks,
    const float* __restrict__ bias, float* __restrict__ hbuf, short* __restrict__ h16,
    const float* __restrict__ gam, const float* __restrict__ bet)
{
  __shared__ float red[256];
  const int row = blockIdx.x, tid = threadIdx.x;
  const long base = (long)row * D_;
  float s0 = hbuf[base + tid] + bias[tid];
  float s1 = hbuf[base + tid + 256] + bias[tid + 256];
  for (int z = 0; z < ks; ++z) {
    s0 += P[(long)z * pstride + base + tid];
    s1 += P[(long)z * pstride + base + tid + 256];
  }
  red[tid] = s0 + s1; __syncthreads();
  for (int o = 128; o > 0; o >>= 1) { if (tid < o) red[tid] += red[tid + o]; __syncthreads(); }
  const float mean = red[0] * (1.0f / D_); __syncthreads();
  const float d0 = s0 - mean, d1 = s1 - mean;
  red[tid] = d0 * d0 + d1 * d1; __syncthreads();
  for (int o = 128; o > 0; o >>= 1) { if (tid < o) red[tid] += red[tid + o]; __syncthreads(); }
  const float inv = rsqrtf(red[0] * (1.0f / D_) + 1e-6f);
  const float v0 = d0 * inv * gam[tid] + bet[tid];
  const float v1 = d1 * inv * gam[tid + 256] + bet[tid + 256];
  hbuf[base + tid] = v0;       h16[base + tid] = f2b(v0);
  hbuf[base + tid + 256] = v1; h16[base + tid + 256] = f2b(v1);
}

// ------- single-pass row softmax (f32 in, bf16 out); causal k<=q; tail -> 0 -------
__global__ __launch_bounds__(256) void softmax_kernel(
    const float* __restrict__ S, short* __restrict__ P, int causal)
{
  __shared__ float red[256];
  const int q = blockIdx.x, bh = blockIdx.y, tid = threadIdx.x;
  const float* row = S + ((size_t)bh * T_ + q) * T_;
  short* prow = P + ((size_t)bh * T_ + q) * T_;
  const int n = causal ? (q + 1) : T_;
  const float v0 = row[tid], v1 = row[tid + 256];
  const bool in0 = tid < n, in1 = (tid + 256) < n;
  red[tid] = fmaxf(in0 ? v0 : -3.0e38f, in1 ? v1 : -3.0e38f);
  __syncthreads();
  for (int o = 128; o > 0; o >>= 1) { if (tid < o) red[tid] = fmaxf(red[tid], red[tid + o]); __syncthreads(); }
  const float m = red[0]; __syncthreads();
  const float e0 = in0 ? expf(v0 - m) : 0.0f;
  const float e1 = in1 ? expf(v1 - m) : 0.0f;
  red[tid] = e0 + e1; __syncthreads();
  for (int o = 128; o > 0; o >>= 1) { if (tid < o) red[tid] += red[tid + o]; __syncthreads(); }
  const float inv = 1.0f / red[0];
  prow[tid] = f2b(e0 * inv);
  prow[tid + 256] = f2b(e1 * inv);
}

extern "C" void kernel_launch(void* const* d_in, const int* in_sizes, int n_in,
                              void* d_out, int out_size, void* d_ws, size_t ws_size,
                              hipStream_t stream)
{
  const int*   x         = (const int*)d_in[0];
  const int*   y         = (const int*)d_in[1];
  const float* enc_emb   = (const float*)d_in[2];
  const float* dec_emb   = (const float*)d_in[3];
  const float* enc_qkv_w = (const float*)d_in[4];
  const float* enc_qkv_b = (const float*)d_in[5];
  const float* enc_out_w = (const float*)d_in[6];
  const float* enc_out_b = (const float*)d_in[7];
  const float* enc_ln1_g = (const float*)d_in[8];
  const float* enc_ln1_b = (const float*)d_in[9];
  const float* enc_ff_w1 = (const float*)d_in[10];
  const float* enc_ff_b1 = (const float*)d_in[11];
  const float* enc_ff_w2 = (const float*)d_in[12];
  const float* enc_ff_b2 = (const float*)d_in[13];
  const float* enc_ln2_g = (const float*)d_in[14];
  const float* enc_ln2_b = (const float*)d_in[15];
  const float* dec_sa_qkv_w = (const float*)d_in[16];
  const float* dec_sa_qkv_b = (const float*)d_in[17];
  const float* dec_sa_out_w = (const float*)d_in[18];
  const float* dec_sa_out_b = (const float*)d_in[19];
  const float* dec_ln1_g = (const float*)d_in[20];
  const float* dec_ln1_b = (const float*)d_in[21];
  const float* dec_ca_qkv_w = (const float*)d_in[22];
  const float* dec_ca_qkv_b = (const float*)d_in[23];
  const float* dec_ca_out_w = (const float*)d_in[24];
  const float* dec_ca_out_b = (const float*)d_in[25];
  const float* dec_ln2_g = (const float*)d_in[26];
  const float* dec_ln2_b = (const float*)d_in[27];
  const float* dec_ff_w1 = (const float*)d_in[28];
  const float* dec_ff_b1 = (const float*)d_in[29];
  const float* dec_ff_w2 = (const float*)d_in[30];
  const float* dec_ff_b2 = (const float*)d_in[31];
  const float* dec_ln3_g = (const float*)d_in[32];
  const float* dec_ln3_b = (const float*)d_in[33];
  const float* head_w    = (const float*)d_in[34];
  const float* head_b    = (const float*)d_in[35];
  float* out = (float*)d_out;

  // ---- workspace carve-up ----
  char* wsb = (char*)d_ws;
  size_t off = 0;
  auto carve = [&](size_t bytes) { char* p = wsb + off; off += (bytes + 255) & ~255ull; return p; };
  float* h    = (float*)carve((size_t)BT_ * D_ * 4);
  float* dd   = (float*)carve((size_t)BT_ * D_ * 4);
  short* hb16 = (short*)carve((size_t)BT_ * D_ * 2);
  short* db16 = (short*)carve((size_t)BT_ * D_ * 2);
  short* Qb   = (short*)carve((size_t)BT_ * HD_ * 2);
  short* Kb   = (short*)carve((size_t)BT_ * HD_ * 2);   // must follow Qb contiguously? no: c_lo handles it
  short* Vt   = (short*)carve((size_t)HD_ * BT_ * 2);
  float* Sb   = (float*)carve((size_t)BH_ * T_ * T_ * 4);  // S + split-K partials
  short* Pb   = (short*)carve((size_t)BH_ * T_ * T_ * 2);
  short* Ob   = Qb;   // Q dead after QK^T
  short* mid  = Qb;   // attn regs dead during FFN
  (void)ws_size;

  dim3 blk(256);
  const long TT  = (long)T_ * T_;
  const long THD = (long)T_ * HD_;
  const long WQKV = (long)D_ * HD_;

  // dispatch helper: bt=BTM, of32=output f32
  auto gemm = [&](bool bt, bool of32,
                  const short* A, long lda, long a_hi, long a_lo,
                  const void* Bp, long ldb, long b_hi, long b_lo,
                  void* Cp, long ldc, long c_hi, long c_lo, long pstride,
                  short* Ct, int trans_hh,
                  int M, int N, int K, int batch, int nh, int ksplit,
                  float scale, const float* bias, long bstride) {
    dim3 grd(N / 128, M / 128, batch * ksplit);
    if (bt) {
      if (of32) mfma_gemm<true , float><<<grd, blk, 0, stream>>>(A, lda, a_hi, a_lo, Bp, ldb, b_hi, b_lo,
          (float*)Cp, ldc, c_hi, c_lo, pstride, Ct, trans_hh, K, nh, ksplit, scale, bias, bstride);
      else      mfma_gemm<true , short><<<grd, blk, 0, stream>>>(A, lda, a_hi, a_lo, Bp, ldb, b_hi, b_lo,
          (short*)Cp, ldc, c_hi, c_lo, pstride, Ct, trans_hh, K, nh, ksplit, scale, bias, bstride);
    } else {
      if (of32) mfma_gemm<false, float><<<grd, blk, 0, stream>>>(A, lda, a_hi, a_lo, Bp, ldb, b_hi, b_lo,
          (float*)Cp, ldc, c_hi, c_lo, pstride, Ct, trans_hh, K, nh, ksplit, scale, bias, bstride);
      else      mfma_gemm<false, short><<<grd, blk, 0, stream>>>(A, lda, a_hi, a_lo, Bp, ldb, b_hi, b_lo,
          (short*)Cp, ldc, c_hi, c_lo, pstride, Ct, trans_hh, K, nh, ksplit, scale, bias, bstride);
    }
  };

  auto attention = [&](const short* qsrc, const short* kvsrc, bool self,
                       const float* qkvw, const float* qkvb,
                       const float* ow, const float* ob,
                       float* resid, short* resid16, int causal,
                       const float* lng, const float* lnb) {
    if (self) {
      // fused Q,K,V (z=3); hh=0->Qb, hh=1->Kb (via c_lo), hh=2 -> transposed Vt
      gemm(false, false, qsrc, D_, 0, 0, qkvw, HD_, 0, WQKV,
           Qb, HD_, 0, (long)(Kb - Qb), 0, Vt, 2,
           BT_, HD_, D_, 3, 3, 1, 1.0f, qkvb, HD_);
    } else {
      gemm(false, false, qsrc, D_, 0, 0, qkvw, HD_, 0, 0,
           Qb, HD_, 0, 0, 0, nullptr, -1,
           BT_, HD_, D_, 1, 1, 1, 1.0f, qkvb, 0);
      // K,V (z=2); hh=0->Kb, hh=1 -> transposed Vt
      gemm(false, false, kvsrc, D_, 0, 0, qkvw + WQKV, HD_, 0, WQKV,
           Kb, HD_, 0, 0, 0, Vt, 1,
           BT_, HD_, D_, 2, 2, 1, 1.0f, qkvb + HD_, HD_);
    }
    // S = Q K^T / sqrt(D)
    gemm(true, true, Qb, HD_, THD, D_, Kb, HD_, THD, D_,
         Sb, T_, (long)H_ * TT, TT, 0, nullptr, -1,
         T_, T_, D_, BH_, H_, 1, 0.044194173824159216f, nullptr, 0);
    softmax_kernel<<<dim3(T_, BH_), blk, 0, stream>>>(Sb, Pb, causal);
    // O = P V  (B = V^T, k-contig)
    gemm(true, false, Pb, T_, (long)H_ * TT, TT, Vt, BT_, T_, (long)D_ * BT_,
         Ob, HD_, THD, D_, 0, nullptr, -1,
         T_, D_, T_, BH_, H_, 1, 1.0f, nullptr, 0);
    // out-projection split-K=8 -> f32 partials in Sb; fused reduce+resid+LN
    gemm(false, true, Ob, HD_, 0, 0, ow, D_, 0, 0,
         Sb, D_, 0, 0, (long)BT_ * D_, nullptr, -1,
         BT_, D_, HD_, 1, 1, 8, 1.0f, nullptr, 0);
    reduce_ln_kernel<<<dim3(BT_), blk, 0, stream>>>(
        Sb, (long)BT_ * D_, 8, ob, resid, resid16, lng, lnb);
  };

  auto ffn = [&](float* resid, short* resid16,
                 const float* w1, const float* b1,
                 const float* w2, const float* b2,
                 const float* lng, const float* lnb) {
    gemm(false, true, resid16, D_, 0, 0, w1, F_, 0, 0,
         Sb, F_, 0, 0, (long)BT_ * F_, nullptr, -1,
         BT_, F_, D_, 1, 1, 2, 1.0f, nullptr, 0);
    reduce_bias_relu_bf16<<<dim3(BT_ * F_ / 1024), blk, 0, stream>>>(
        Sb, (long)BT_ * F_, 2, b1, mid, (long)BT_ * F_, F_);
    gemm(false, true, mid, F_, 0, 0, w2, D_, 0, 0,
         Sb, D_, 0, 0, (long)BT_ * D_, nullptr, -1,
         BT_, D_, F_, 1, 1, 8, 1.0f, nullptr, 0);
    reduce_ln_kernel<<<dim3(BT_), blk, 0, stream>>>(
        Sb, (long)BT_ * D_, 8, b2, resid, resid16, lng, lnb);
  };

  // ---------------- encoder ----------------
  embed_kernel<<<dim3(BT_), blk, 0, stream>>>(x, enc_emb, h, hb16);
  for (int i = 0; i < L_; ++i) {
    attention(hb16, hb16, true,
              enc_qkv_w + (size_t)i * 3 * WQKV, enc_qkv_b + (size_t)i * 3 * HD_,
              enc_out_w + (size_t)i * HD_ * D_, enc_out_b + (size_t)i * D_,
              h, hb16, 0, enc_ln1_g + (size_t)i * D_, enc_ln1_b + (size_t)i * D_);
    ffn(h, hb16, enc_ff_w1 + (size_t)i * D_ * F_, enc_ff_b1 + (size_t)i * F_,
        enc_ff_w2 + (size_t)i * F_ * D_, enc_ff_b2 + (size_t)i * D_,
        enc_ln2_g + (size_t)i * D_, enc_ln2_b + (size_t)i * D_);
  }

  // ---------------- decoder ----------------
  embed_kernel<<<dim3(BT_), blk, 0, stream>>>(y, dec_emb, dd, db16);
  for (int i = 0; i < L_; ++i) {
    attention(db16, db16, true,
              dec_sa_qkv_w + (size_t)i * 3 * WQKV, dec_sa_qkv_b + (size_t)i * 3 * HD_,
              dec_sa_out_w + (size_t)i * HD_ * D_, dec_sa_out_b + (size_t)i * D_,
              dd, db16, 1, dec_ln1_g + (size_t)i * D_, dec_ln1_b + (size_t)i * D_);
    attention(db16, hb16, false,
              dec_ca_qkv_w + (size_t)i * 3 * WQKV, dec_ca_qkv_b + (size_t)i * 3 * HD_,
              dec_ca_out_w + (size_t)i * HD_ * D_, dec_ca_out_b + (size_t)i * D_,
              dd, db16, 0, dec_ln2_g + (size_t)i * D_, dec_ln2_b + (size_t)i * D_);
    ffn(dd, db16, dec_ff_w1 + (size_t)i * D_ * F_, dec_ff_b1 + (size_t)i * F_,
        dec_ff_w2 + (size_t)i * F_ * D_, dec_ff_b2 + (size_t)i * D_,
        dec_ln3_g + (size_t)i * D_, dec_ln3_b + (size_t)i * D_);
  }

  // ---------------- LM head -> f32 logits ----------------
  gemm(false, true, db16, D_, 0, 0, head_w, V_, 0, 0,
       out, V_, 0, 0, 0, nullptr, -1,
       BT_, V_, D_, 1, 1, 1, 1.0f, head_b, 0);
}

// Round 6
// 2392.328 us; speedup vs baseline: 5.8178x; 1.0043x over previous
//
#include <hip/hip_runtime.h>
#include <hip/hip_bf16.h>

#define B_ 2
#define T_ 512
#define D_ 512
#define H_ 8
#define L_ 6
#define F_ 2048
#define V_ 32000
#define BT_ (B_ * T_)
#define HD_ (H_ * D_)
#define BH_ (B_ * H_)

typedef __attribute__((ext_vector_type(8))) short short8;
typedef __attribute__((ext_vector_type(4))) short short4v;
typedef __attribute__((ext_vector_type(4))) float f32x4;

__device__ __forceinline__ short f2b(float f) {
  __hip_bfloat16 h = __float2bfloat16(f);
  short u; __builtin_memcpy(&u, &h, 2); return u;
}
__device__ __forceinline__ void store_c(float* p, float v) { *p = v; }
__device__ __forceinline__ void store_c(short* p, float v) { *p = f2b(v); }

// ---------------- embedding * sqrt(D) + sinusoidal PE (f32 + bf16 copies) ----------------
__global__ __launch_bounds__(256) void embed_kernel(
    const int* __restrict__ tok, const float* __restrict__ emb,
    float* __restrict__ out, short* __restrict__ out16)
{
  const int row = blockIdx.x;            // b*T + t
  const int t = row & (T_ - 1);
  const int token = tok[row];
  const float* e = emb + (size_t)token * D_;
  float* o = out + (size_t)row * D_;
  short* o16 = out16 + (size_t)row * D_;
  const float scale = sqrtf((float)D_);
  const float nl = -logf(10000.0f);
  for (int d = threadIdx.x; d < D_; d += 256) {
    int i = d >> 1;
    float wl = expf(nl * (2.0f * (float)i) / (float)D_);
    float ang = (float)t * wl;
    float pe = (d & 1) ? cosf(ang) : sinf(ang);
    float v = e[d] * scale + pe;
    o[d] = v; o16[d] = f2b(v);
  }
}

// ---------------- generic MFMA GEMM ----------------
// A: bf16 [.,K] k-contig. B: BTM ? bf16 [N][K] k-contig : f32 [K][N].
// BM in {64,128}, BN=128. 4 waves: BM=128 -> 2x2 waves of 64x64;
// BM=64 -> 1x4 waves of 64x32. Single-buffer LDS + reg prefetch.
// z = batch(nh) x ksplit. Optional transposed bf16 store for hh==trans_hh.
template<bool BTM, typename OutT, int BM>
__global__ __launch_bounds__(256, 3) void mfma_gemm(
    const short* __restrict__ A, long lda, long a_hi, long a_lo,
    const void* __restrict__ Bv, long ldb, long b_hi, long b_lo,
    OutT* __restrict__ C, long ldc, long c_hi, long c_lo, long pstride,
    short* __restrict__ Ct, int trans_hh,
    int K, int nh, int ksplit, float scale,
    const float* __restrict__ bias, long bias_stride)
{
  constexpr int SA = BM + 1;            // A LDS chunk stride (bank-spread)
  constexpr int AU = BM / 32;           // A staging octs per thread
  constexpr int WRN = (BM == 128) ? 2 : 1;
  constexpr int WN  = 128 / (4 / WRN);  // per-wave N extent: 64 or 32
  constexpr int NR  = WN / 16;          // 4 or 2
  __shared__ short8 As8[8 * SA];
  __shared__ short8 Bs8[8 * 129];
  const int tid = threadIdx.x;
  const int bh = blockIdx.z / ksplit;
  const int kz = blockIdx.z - bh * ksplit;
  const int bb = bh / nh, hh = bh - bb * nh;
  const short* Ab = A + (long)bb * a_hi + (long)hh * a_lo;
  const short* Bbs = (const short*)Bv + (long)bb * b_hi + (long)hh * b_lo;
  const float* Bbf = (const float*)Bv + (long)bb * b_hi + (long)hh * b_lo;
  OutT* Cb = C + (long)bb * c_hi + (long)hh * c_lo + (long)kz * pstride;

  // XCD-chunked bijective swizzle, y-major (same-N-panel blocks share an XCD L2)
  const int gx = gridDim.x, gy = gridDim.y;
  const int nwg = gx * gy;
  int lin = blockIdx.y * gx + blockIdx.x;
  {
    const int xcd = lin & 7, idx = lin >> 3;
    const int q = nwg >> 3, r = nwg & 7;
    lin = (xcd < r ? xcd * (q + 1) : r * (q + 1) + (xcd - r) * q) + idx;
  }
  const int bn = (lin / gy) * 128;
  const int bm = (lin % gy) * BM;

  const int klen = K / ksplit, kbase = kz * klen;
  const int lane = tid & 63, wid = tid >> 6;
  const int wr = (WRN == 2) ? (wid >> 1) : 0;
  const int wc = (WRN == 2) ? (wid & 1) : wid;
  const int lg = lane >> 4, r16 = lane & 15;

  int arow[AU], acol[AU];
#pragma unroll
  for (int u = 0; u < AU; ++u) { int o = u * 256 + tid; arow[u] = o >> 3; acol[u] = o & 7; }
  const int ncol = tid & 127, nsh = tid >> 7;

  short8 pa[AU];
  short8 pbt[4];
  float  pbn[4][8];

  auto load = [&](int k0) {
#pragma unroll
    for (int u = 0; u < AU; ++u)
      pa[u] = *(const short8*)(Ab + (long)(bm + arow[u]) * lda + (k0 + acol[u] * 8));
    if constexpr (BTM) {
#pragma unroll
      for (int u = 0; u < 4; ++u)
        pbt[u] = *(const short8*)(Bbs + (long)(bn + (u * 256 + tid) / 8) * ldb + (k0 + ((u * 256 + tid) & 7) * 8));
    } else {
      const float* s = Bbf + (long)(k0 + nsh * 32) * ldb + (bn + ncol);
#pragma unroll
      for (int i = 0; i < 4; ++i)
#pragma unroll
        for (int j = 0; j < 8; ++j)
          pbn[i][j] = s[(long)(i * 8 + j) * ldb];
    }
  };
  auto stage = [&]() {
#pragma unroll
    for (int u = 0; u < AU; ++u) As8[acol[u] * SA + arow[u]] = pa[u];
    if constexpr (BTM) {
#pragma unroll
      for (int u = 0; u < 4; ++u)
        Bs8[((u * 256 + tid) & 7) * 129 + (u * 256 + tid) / 8] = pbt[u];
    } else {
#pragma unroll
      for (int i = 0; i < 4; ++i) {
        short8 v;
#pragma unroll
        for (int j = 0; j < 8; ++j) v[j] = f2b(pbn[i][j]);
        Bs8[(nsh * 4 + i) * 129 + ncol] = v;
      }
    }
  };

  f32x4 acc[4][NR] = {};
  auto domfma = [&]() {
#pragma unroll
    for (int kb = 0; kb < 2; ++kb) {
      const int cha = (kb * 4 + lg) * SA;
      const int chb = (kb * 4 + lg) * 129;
      short8 a0 = As8[cha + wr * 64 +  0 + r16];
      short8 a1 = As8[cha + wr * 64 + 16 + r16];
      short8 a2 = As8[cha + wr * 64 + 32 + r16];
      short8 a3 = As8[cha + wr * 64 + 48 + r16];
#pragma unroll
      for (int n = 0; n < NR; ++n) {
        short8 bfr = Bs8[chb + wc * WN + n * 16 + r16];
        acc[0][n] = __builtin_amdgcn_mfma_f32_16x16x32_bf16(a0, bfr, acc[0][n], 0, 0, 0);
        acc[1][n] = __builtin_amdgcn_mfma_f32_16x16x32_bf16(a1, bfr, acc[1][n], 0, 0, 0);
        acc[2][n] = __builtin_amdgcn_mfma_f32_16x16x32_bf16(a2, bfr, acc[2][n], 0, 0, 0);
        acc[3][n] = __builtin_amdgcn_mfma_f32_16x16x32_bf16(a3, bfr, acc[3][n], 0, 0, 0);
      }
    }
  };

  load(kbase);
  stage();
  __syncthreads();
  const int nsteps = klen >> 6;
  for (int t = 0; t < nsteps; ++t) {
    const bool more = (t + 1 < nsteps);
    if (more) load(kbase + (t + 1) * 64);
    domfma();
    if (more) { __syncthreads(); stage(); __syncthreads(); }
  }

  const float* bp = bias ? bias + (long)hh * bias_stride : nullptr;
  if (hh == trans_hh) {
    // transposed bf16 store: Ct[col][row]
#pragma unroll
    for (int m = 0; m < 4; ++m)
#pragma unroll
      for (int n = 0; n < NR; ++n) {
        const int col = bn + wc * WN + n * 16 + r16;
        const float badd = bp ? bp[col] : 0.0f;
        short4v sv;
#pragma unroll
        for (int rr = 0; rr < 4; ++rr) sv[rr] = f2b(acc[m][n][rr] * scale + badd);
        *(short4v*)(Ct + (long)col * BT_ + (bm + wr * 64 + m * 16 + lg * 4)) = sv;
      }
  } else {
#pragma unroll
    for (int m = 0; m < 4; ++m)
#pragma unroll
      for (int rr = 0; rr < 4; ++rr) {
        const int row = bm + wr * 64 + m * 16 + lg * 4 + rr;
        OutT* crow = Cb + (long)row * ldc + bn + wc * WN + r16;
#pragma unroll
        for (int n = 0; n < NR; ++n) {
          float v = acc[m][n][rr] * scale;
          if (bp) v += bp[bn + wc * WN + n * 16 + r16];
          store_c(&crow[n * 16], v);
        }
      }
  }
}

// ---------------- split-K reduce + bias + relu -> bf16 (FFN mid) ----------------
__global__ __launch_bounds__(256) void reduce_bias_relu_bf16(
    const float* __restrict__ P, long pstride, int ks,
    const float* __restrict__ bias, short* __restrict__ out, long mn, int N)
{
  const long i = ((long)blockIdx.x * 256 + threadIdx.x) * 4;
  if (i >= mn) return;
  float4 s = *(const float4*)(P + i);
  for (int z = 1; z < ks; ++z) {
    float4 t = *(const float4*)(P + (long)z * pstride + i);
    s.x += t.x; s.y += t.y; s.z += t.z; s.w += t.w;
  }
  const int col = (int)(i % N);
  s.x += bias[col]; s.y += bias[col + 1]; s.z += bias[col + 2]; s.w += bias[col + 3];
  short4v o;
  o[0] = f2b(fmaxf(s.x, 0.f)); o[1] = f2b(fmaxf(s.y, 0.f));
  o[2] = f2b(fmaxf(s.z, 0.f)); o[3] = f2b(fmaxf(s.w, 0.f));
  *(short4v*)(out + i) = o;
}

// ---- fused: x = resid + bias + sum_z partial; resid(f32) = LN(x)*g+b; + bf16 copy ----
__global__ __launch_bounds__(256) void reduce_ln_kernel(
    const float* __restrict__ P, long pstride, int ks,
    const float* __restrict__ bias, float* __restrict__ hbuf, short* __restrict__ h16,
    const float* __restrict__ gam, const float* __restrict__ bet)
{
  __shared__ float red[256];
  const int row = blockIdx.x, tid = threadIdx.x;
  const long base = (long)row * D_;
  float s0 = hbuf[base + tid] + bias[tid];
  float s1 = hbuf[base + tid + 256] + bias[tid + 256];
  for (int z = 0; z < ks; ++z) {
    s0 += P[(long)z * pstride + base + tid];
    s1 += P[(long)z * pstride + base + tid + 256];
  }
  red[tid] = s0 + s1; __syncthreads();
  for (int o = 128; o > 0; o >>= 1) { if (tid < o) red[tid] += red[tid + o]; __syncthreads(); }
  const float mean = red[0] * (1.0f / D_); __syncthreads();
  const float d0 = s0 - mean, d1 = s1 - mean;
  red[tid] = d0 * d0 + d1 * d1; __syncthreads();
  for (int o = 128; o > 0; o >>= 1) { if (tid < o) red[tid] += red[tid + o]; __syncthreads(); }
  const float inv = rsqrtf(red[0] * (1.0f / D_) + 1e-6f);
  const float v0 = d0 * inv * gam[tid] + bet[tid];
  const float v1 = d1 * inv * gam[tid + 256] + bet[tid + 256];
  hbuf[base + tid] = v0;       h16[base + tid] = f2b(v0);
  hbuf[base + tid + 256] = v1; h16[base + tid + 256] = f2b(v1);
}

// ------- single-pass row softmax (f32 in, bf16 out); causal k<=q; tail -> 0 -------
__global__ __launch_bounds__(256) void softmax_kernel(
    const float* __restrict__ S, short* __restrict__ P, int causal)
{
  __shared__ float red[256];
  const int q = blockIdx.x, bh = blockIdx.y, tid = threadIdx.x;
  const float* row = S + ((size_t)bh * T_ + q) * T_;
  short* prow = P + ((size_t)bh * T_ + q) * T_;
  const int n = causal ? (q + 1) : T_;
  const float v0 = row[tid], v1 = row[tid + 256];
  const bool in0 = tid < n, in1 = (tid + 256) < n;
  red[tid] = fmaxf(in0 ? v0 : -3.0e38f, in1 ? v1 : -3.0e38f);
  __syncthreads();
  for (int o = 128; o > 0; o >>= 1) { if (tid < o) red[tid] = fmaxf(red[tid], red[tid + o]); __syncthreads(); }
  const float m = red[0]; __syncthreads();
  const float e0 = in0 ? expf(v0 - m) : 0.0f;
  const float e1 = in1 ? expf(v1 - m) : 0.0f;
  red[tid] = e0 + e1; __syncthreads();
  for (int o = 128; o > 0; o >>= 1) { if (tid < o) red[tid] += red[tid + o]; __syncthreads(); }
  const float inv = 1.0f / red[0];
  prow[tid] = f2b(e0 * inv);
  prow[tid + 256] = f2b(e1 * inv);
}

extern "C" void kernel_launch(void* const* d_in, const int* in_sizes, int n_in,
                              void* d_out, int out_size, void* d_ws, size_t ws_size,
                              hipStream_t stream)
{
  const int*   x         = (const int*)d_in[0];
  const int*   y         = (const int*)d_in[1];
  const float* enc_emb   = (const float*)d_in[2];
  const float* dec_emb   = (const float*)d_in[3];
  const float* enc_qkv_w = (const float*)d_in[4];
  const float* enc_qkv_b = (const float*)d_in[5];
  const float* enc_out_w = (const float*)d_in[6];
  const float* enc_out_b = (const float*)d_in[7];
  const float* enc_ln1_g = (const float*)d_in[8];
  const float* enc_ln1_b = (const float*)d_in[9];
  const float* enc_ff_w1 = (const float*)d_in[10];
  const float* enc_ff_b1 = (const float*)d_in[11];
  const float* enc_ff_w2 = (const float*)d_in[12];
  const float* enc_ff_b2 = (const float*)d_in[13];
  const float* enc_ln2_g = (const float*)d_in[14];
  const float* enc_ln2_b = (const float*)d_in[15];
  const float* dec_sa_qkv_w = (const float*)d_in[16];
  const float* dec_sa_qkv_b = (const float*)d_in[17];
  const float* dec_sa_out_w = (const float*)d_in[18];
  const float* dec_sa_out_b = (const float*)d_in[19];
  const float* dec_ln1_g = (const float*)d_in[20];
  const float* dec_ln1_b = (const float*)d_in[21];
  const float* dec_ca_qkv_w = (const float*)d_in[22];
  const float* dec_ca_qkv_b = (const float*)d_in[23];
  const float* dec_ca_out_w = (const float*)d_in[24];
  const float* dec_ca_out_b = (const float*)d_in[25];
  const float* dec_ln2_g = (const float*)d_in[26];
  const float* dec_ln2_b = (const float*)d_in[27];
  const float* dec_ff_w1 = (const float*)d_in[28];
  const float* dec_ff_b1 = (const float*)d_in[29];
  const float* dec_ff_w2 = (const float*)d_in[30];
  const float* dec_ff_b2 = (const float*)d_in[31];
  const float* dec_ln3_g = (const float*)d_in[32];
  const float* dec_ln3_b = (const float*)d_in[33];
  const float* head_w    = (const float*)d_in[34];
  const float* head_b    = (const float*)d_in[35];
  float* out = (float*)d_out;

  // ---- workspace carve-up ----
  char* wsb = (char*)d_ws;
  size_t off = 0;
  auto carve = [&](size_t bytes) { char* p = wsb + off; off += (bytes + 255) & ~255ull; return p; };
  float* h    = (float*)carve((size_t)BT_ * D_ * 4);
  float* dd   = (float*)carve((size_t)BT_ * D_ * 4);
  short* hb16 = (short*)carve((size_t)BT_ * D_ * 2);
  short* db16 = (short*)carve((size_t)BT_ * D_ * 2);
  short* Qb   = (short*)carve((size_t)BT_ * HD_ * 2);
  short* Kb   = (short*)carve((size_t)BT_ * HD_ * 2);
  short* Vt   = (short*)carve((size_t)HD_ * BT_ * 2);
  float* Sb   = (float*)carve((size_t)BH_ * T_ * T_ * 4);  // S + split-K partials
  short* Pb   = (short*)carve((size_t)BH_ * T_ * T_ * 2);
  short* Ob   = Qb;   // Q dead after QK^T
  short* mid  = Qb;   // attn regs dead during FFN
  (void)ws_size;

  dim3 blk(256);
  const long TT  = (long)T_ * T_;
  const long THD = (long)T_ * HD_;
  const long WQKV = (long)D_ * HD_;

  // dispatch helper: bt=BTM, of32=output f32, bm64=use 64-row tile
  auto gemm = [&](bool bt, bool of32, bool bm64,
                  const short* A, long lda, long a_hi, long a_lo,
                  const void* Bp, long ldb, long b_hi, long b_lo,
                  void* Cp, long ldc, long c_hi, long c_lo, long pstride,
                  short* Ct, int trans_hh,
                  int M, int N, int K, int batch, int nh, int ksplit,
                  float scale, const float* bias, long bstride) {
    dim3 grd(N / 128, M / (bm64 ? 64 : 128), batch * ksplit);
    if (bm64) {
      if (bt) {
        if (of32) mfma_gemm<true , float, 64><<<grd, blk, 0, stream>>>(A, lda, a_hi, a_lo, Bp, ldb, b_hi, b_lo,
            (float*)Cp, ldc, c_hi, c_lo, pstride, Ct, trans_hh, K, nh, ksplit, scale, bias, bstride);
        else      mfma_gemm<true , short, 64><<<grd, blk, 0, stream>>>(A, lda, a_hi, a_lo, Bp, ldb, b_hi, b_lo,
            (short*)Cp, ldc, c_hi, c_lo, pstride, Ct, trans_hh, K, nh, ksplit, scale, bias, bstride);
      } else {
        if (of32) mfma_gemm<false, float, 64><<<grd, blk, 0, stream>>>(A, lda, a_hi, a_lo, Bp, ldb, b_hi, b_lo,
            (float*)Cp, ldc, c_hi, c_lo, pstride, Ct, trans_hh, K, nh, ksplit, scale, bias, bstride);
        else      mfma_gemm<false, short, 64><<<grd, blk, 0, stream>>>(A, lda, a_hi, a_lo, Bp, ldb, b_hi, b_lo,
            (short*)Cp, ldc, c_hi, c_lo, pstride, Ct, trans_hh, K, nh, ksplit, scale, bias, bstride);
      }
    } else {
      if (of32) mfma_gemm<false, float, 128><<<grd, blk, 0, stream>>>(A, lda, a_hi, a_lo, Bp, ldb, b_hi, b_lo,
          (float*)Cp, ldc, c_hi, c_lo, pstride, Ct, trans_hh, K, nh, ksplit, scale, bias, bstride);
      else      mfma_gemm<false, short, 128><<<grd, blk, 0, stream>>>(A, lda, a_hi, a_lo, Bp, ldb, b_hi, b_lo,
          (short*)Cp, ldc, c_hi, c_lo, pstride, Ct, trans_hh, K, nh, ksplit, scale, bias, bstride);
    }
  };

  auto attention = [&](const short* qsrc, const short* kvsrc, bool self,
                       const float* qkvw, const float* qkvb,
                       const float* ow, const float* ob,
                       float* resid, short* resid16, int causal,
                       const float* lng, const float* lnb) {
    if (self) {
      // fused Q,K,V (z=3); hh=0->Qb, hh=1->Kb (via c_lo), hh=2 -> transposed Vt
      gemm(false, false, true, qsrc, D_, 0, 0, qkvw, HD_, 0, WQKV,
           Qb, HD_, 0, (long)(Kb - Qb), 0, Vt, 2,
           BT_, HD_, D_, 3, 3, 1, 1.0f, qkvb, HD_);
    } else {
      gemm(false, false, true, qsrc, D_, 0, 0, qkvw, HD_, 0, 0,
           Qb, HD_, 0, 0, 0, nullptr, -1,
           BT_, HD_, D_, 1, 1, 1, 1.0f, qkvb, 0);
      gemm(false, false, true, kvsrc, D_, 0, 0, qkvw + WQKV, HD_, 0, WQKV,
           Kb, HD_, 0, 0, 0, Vt, 1,
           BT_, HD_, D_, 2, 2, 1, 1.0f, qkvb + HD_, HD_);
    }
    // S = Q K^T / sqrt(D)
    gemm(true, true, true, Qb, HD_, THD, D_, Kb, HD_, THD, D_,
         Sb, T_, (long)H_ * TT, TT, 0, nullptr, -1,
         T_, T_, D_, BH_, H_, 1, 0.044194173824159216f, nullptr, 0);
    softmax_kernel<<<dim3(T_, BH_), blk, 0, stream>>>(Sb, Pb, causal);
    // O = P V  (B = V^T, k-contig)
    gemm(true, false, true, Pb, T_, (long)H_ * TT, TT, Vt, BT_, T_, (long)D_ * BT_,
         Ob, HD_, THD, D_, 0, nullptr, -1,
         T_, D_, T_, BH_, H_, 1, 1.0f, nullptr, 0);
    // out-projection split-K=8 -> f32 partials in Sb; fused reduce+resid+LN
    gemm(false, true, true, Ob, HD_, 0, 0, ow, D_, 0, 0,
         Sb, D_, 0, 0, (long)BT_ * D_, nullptr, -1,
         BT_, D_, HD_, 1, 1, 8, 1.0f, nullptr, 0);
    reduce_ln_kernel<<<dim3(BT_), blk, 0, stream>>>(
        Sb, (long)BT_ * D_, 8, ob, resid, resid16, lng, lnb);
  };

  auto ffn = [&](float* resid, short* resid16,
                 const float* w1, const float* b1,
                 const float* w2, const float* b2,
                 const float* lng, const float* lnb) {
    gemm(false, true, true, resid16, D_, 0, 0, w1, F_, 0, 0,
         Sb, F_, 0, 0, (long)BT_ * F_, nullptr, -1,
         BT_, F_, D_, 1, 1, 2, 1.0f, nullptr, 0);
    reduce_bias_relu_bf16<<<dim3(BT_ * F_ / 1024), blk, 0, stream>>>(
        Sb, (long)BT_ * F_, 2, b1, mid, (long)BT_ * F_, F_);
    gemm(false, true, true, mid, F_, 0, 0, w2, D_, 0, 0,
         Sb, D_, 0, 0, (long)BT_ * D_, nullptr, -1,
         BT_, D_, F_, 1, 1, 8, 1.0f, nullptr, 0);
    reduce_ln_kernel<<<dim3(BT_), blk, 0, stream>>>(
        Sb, (long)BT_ * D_, 8, b2, resid, resid16, lng, lnb);
  };

  // ---------------- encoder ----------------
  embed_kernel<<<dim3(BT_), blk, 0, stream>>>(x, enc_emb, h, hb16);
  for (int i = 0; i < L_; ++i) {
    attention(hb16, hb16, true,
              enc_qkv_w + (size_t)i * 3 * WQKV, enc_qkv_b + (size_t)i * 3 * HD_,
              enc_out_w + (size_t)i * HD_ * D_, enc_out_b + (size_t)i * D_,
              h, hb16, 0, enc_ln1_g + (size_t)i * D_, enc_ln1_b + (size_t)i * D_);
    ffn(h, hb16, enc_ff_w1 + (size_t)i * D_ * F_, enc_ff_b1 + (size_t)i * F_,
        enc_ff_w2 + (size_t)i * F_ * D_, enc_ff_b2 + (size_t)i * D_,
        enc_ln2_g + (size_t)i * D_, enc_ln2_b + (size_t)i * D_);
  }

  // ---------------- decoder ----------------
  embed_kernel<<<dim3(BT_), blk, 0, stream>>>(y, dec_emb, dd, db16);
  for (int i = 0; i < L_; ++i) {
    attention(db16, db16, true,
              dec_sa_qkv_w + (size_t)i * 3 * WQKV, dec_sa_qkv_b + (size_t)i * 3 * HD_,
              dec_sa_out_w + (size_t)i * HD_ * D_, dec_sa_out_b + (size_t)i * D_,
              dd, db16, 1, dec_ln1_g + (size_t)i * D_, dec_ln1_b + (size_t)i * D_);
    attention(db16, hb16, false,
              dec_ca_qkv_w + (size_t)i * 3 * WQKV, dec_ca_qkv_b + (size_t)i * 3 * HD_,
              dec_ca_out_w + (size_t)i * HD_ * D_, dec_ca_out_b + (size_t)i * D_,
              dd, db16, 0, dec_ln2_g + (size_t)i * D_, dec_ln2_b + (size_t)i * D_);
    ffn(dd, db16, dec_ff_w1 + (size_t)i * D_ * F_, dec_ff_b1 + (size_t)i * F_,
        dec_ff_w2 + (size_t)i * F_ * D_, dec_ff_b2 + (size_t)i * D_,
        dec_ln3_g + (size_t)i * D_, dec_ln3_b + (size_t)i * D_);
  }

  // ---------------- LM head -> f32 logits ----------------
  gemm(false, true, false, db16, D_, 0, 0, head_w, V_, 0, 0,
       out, V_, 0, 0, 0, nullptr, -1,
       BT_, V_, D_, 1, 1, 1, 1.0f, head_b, 0);
}